// Round 13
// baseline (573.429 us; speedup 1.0000x reference)
//
#include <hip/hip_runtime.h>

typedef __attribute__((ext_vector_type(8))) short s16x8;
typedef __attribute__((ext_vector_type(4))) short s16x4;
typedef __attribute__((ext_vector_type(4))) float f32x4;
typedef __attribute__((ext_vector_type(16))) float f32x16;
typedef __attribute__((ext_vector_type(2))) unsigned uint2v;

#define DEVINL __device__ __forceinline__

// ---------- bf16 helpers ----------
DEVINL float b2f(short u){ return __uint_as_float(((unsigned)(unsigned short)u) << 16); }
DEVINL short f2bf(float f){
  unsigned u = __float_as_uint(f);
  u += 0x7fffu + ((u >> 16) & 1u);
  return (short)(u >> 16);
}
DEVINL unsigned cvtpk(float lo, float hi){
  unsigned r;
  asm("v_cvt_pk_bf16_f32 %0, %1, %2" : "=v"(r) : "v"(lo), "v"(hi));
  return r;
}
DEVINL float max3f(float a, float b, float c){
  float r; asm("v_max3_f32 %0, %1, %2, %3" : "=v"(r) : "v"(a), "v"(b), "v"(c)); return r;
}

#if __has_builtin(__builtin_amdgcn_exp2f)
#define EXP2F __builtin_amdgcn_exp2f
#else
#define EXP2F exp2f
#endif

// ---------- MFMA wrappers ----------
DEVINL f32x4 mfma32(s16x8 a, s16x8 b, f32x4 c){
  return __builtin_amdgcn_mfma_f32_16x16x32_bf16(a, b, c, 0, 0, 0);
}
DEVINL f32x16 mfma3216(s16x8 a, s16x8 b, f32x16 c){
  return __builtin_amdgcn_mfma_f32_32x32x16_bf16(a, b, c, 0, 0, 0);
}

DEVINL uint2v pl32swap(unsigned a, unsigned b){
#if __has_builtin(__builtin_amdgcn_permlane32_swap)
  return __builtin_amdgcn_permlane32_swap(a, b, false, false);
#else
  asm volatile("v_permlane32_swap_b32 %0, %1" : "+v"(a), "+v"(b));
  uint2v r; r[0] = a; r[1] = b; return r;
#endif
}

// ---------- async global->LDS (width 16) ----------
typedef const unsigned __attribute__((address_space(1)))* gas1;
typedef unsigned __attribute__((address_space(3)))* las3;
DEVINL void gload16(const short* g, short* l){
  __builtin_amdgcn_global_load_lds((gas1)g, (las3)l, 16, 0, 0);
}

// ---------- sync primitives ----------
#define CFENCE asm volatile("" ::: "memory")
#define PBAR  do{ CFENCE; __builtin_amdgcn_sched_barrier(0); __builtin_amdgcn_s_barrier(); \
                  __builtin_amdgcn_sched_barrier(0); CFENCE; }while(0)
#define VMW4 asm volatile("s_waitcnt vmcnt(4)" ::: "memory")
#define VMW0 asm volatile("s_waitcnt vmcnt(0)" ::: "memory")
#define PRIO1 __builtin_amdgcn_s_setprio(1)
#define PRIO0 __builtin_amdgcn_s_setprio(0)

// ---------- problem constants ----------
static const int Bc   = 4;
static const int Nc   = 2048;
static const int DIM  = 1024;
static const int Tc   = Bc * Nc;      // 8192 tokens
static const int MLP  = 4096;
static const int D3   = 3072;

// ---------- ws layout (bytes) ----------
static const size_t OFF_XB    = 0;
static const size_t OFF_WQKVT = OFF_XB    + 16777216;
static const size_t OFF_W1T   = OFF_WQKVT + 6291456;
static const size_t OFF_W2T   = OFF_W1T   + 8388608;
static const size_t OFF_WOUTT = OFF_W2T   + 8388608;
static const size_t OFF_QKV   = OFF_WOUTT + 2097152;
static const size_t OFF_QLN   = OFF_QKV   + 50331648;
static const size_t OFF_KLN   = OFF_QLN   + 16777216;
static const size_t OFF_VT    = OFF_KLN   + 16777216;
static const size_t OFF_ATTNV = OFF_VT    + 16777216;
static const size_t OFF_H     = OFF_QKV;   // hbuf over dead qkv+qln (after attn)
static const size_t OFF_S2    = OFF_KLN;   // fused MLP2+Wout output over dead kln

// ============================================================
// x fp32 -> bf16
// ============================================================
__global__ __launch_bounds__(256) void conv_x(const float* __restrict__ x, short* __restrict__ xb){
  size_t i = ((size_t)blockIdx.x * 256 + threadIdx.x) * 8;
  f32x4 v0 = *(const f32x4*)(x + i);
  f32x4 v1 = *(const f32x4*)(x + i + 4);
  s16x8 o;
#pragma unroll
  for (int j = 0; j < 4; ++j){ o[j] = f2bf(v0[j]); o[4+j] = f2bf(v1[j]); }
  *(s16x8*)(xb + i) = o;
}

// ============================================================
// W[K][N] fp32 -> Wt[N][K] bf16
// ============================================================
__global__ __launch_bounds__(256) void transpose_conv(const float* __restrict__ W, short* __restrict__ Wt,
                                                      int K, int N){
  __shared__ float tile[32][33];
  int ntx = N >> 5;
  int tx = blockIdx.x % ntx, ty = blockIdx.x / ntx;
  int r = threadIdx.x >> 3, c = (threadIdx.x & 7) * 4;
  f32x4 v = *(const f32x4*)(W + (size_t)(ty*32 + r)*N + tx*32 + c);
  tile[r][c] = v[0]; tile[r][c+1] = v[1]; tile[r][c+2] = v[2]; tile[r][c+3] = v[3];
  __syncthreads();
  s16x4 o;
#pragma unroll
  for (int j = 0; j < 4; ++j) o[j] = f2bf(tile[c+j][r]);
  *(s16x4*)(Wt + (size_t)(tx*32 + r)*K + ty*32 + c) = o;
}

// ============================================================
// gemmCF — R13: 3-SLOT ring (48KB LDS -> 3 blocks/CU, 12 waves) instead of
// the R7-R12 4-slot/64KB/2-block version. Same per-phase work (8 ds_read,
// 4 gload16, 16 MFMA), same counted-vmcnt ledger:
//   prologue stages half-tiles 0,1 (8 loads), vmcnt(4) certifies tile 0;
//   phase p reads slot sA, stages half-tile p+2 into sC (4 loads);
//   end-of-phase vmcnt(4) drains the oldest 4 = next phase's slot;
//   p=NP-2 -> vmcnt(0); p=NP-1 -> none. WAR: staged slot's last reads
//   completed before the previous phase's closing barrier.
// FUSED: half-tile p reads segment 2 when p >= NP1.
// QKVEPI: q/k LN(d=64)+reorg or V-transpose epilogue (R12, unchanged).
// ============================================================
template<int ACT, int FUSED, int QKVEPI>
__global__ __launch_bounds__(256, 3) void gemmCF(const short* __restrict__ A, const short* __restrict__ A2,
                                                 const short* __restrict__ Bt, const short* __restrict__ Bt2,
                                                 short* __restrict__ C,
                                                 const float* __restrict__ bias, const float* __restrict__ bias2,
                                                 int M, int N, int K1, int K2,
                                                 short* __restrict__ qln, short* __restrict__ kln,
                                                 short* __restrict__ vtb){
  __shared__ short lds[24576];   // A slots: 3 x 4096 shorts; B: 12288 + 3 x 4096

  const int tid = threadIdx.x;
  const int w = tid >> 6, lane = tid & 63;
  const int lr = lane & 15, g = lane >> 4;
  const int wr = w >> 1, wc = w & 1;
  const int NP1 = K1 >> 5;                      // half-tile phases in segment 1
  const int NP = NP1 + (FUSED ? (K2 >> 5) : 0); // total phases (32 cols each)

  const int nbn = N >> 7;
  const int cpx = gridDim.x >> 3;
  const int bid = (int)blockIdx.x;
  const int sw = (bid & 7)*cpx + (bid >> 3);
  const int nbn8 = nbn >> 3;
  const int T8 = sw >> 6, t64 = sw & 63;
  const int bm = (T8 / nbn8)*8 + (t64 >> 3);
  const int bn = (T8 % nbn8)*8 + (t64 & 7);

  const int l2 = lane >> 2;
  const int gsw = ((lane & 3) - ((lane >> 3) & 3)) & 3;
  const int cof = gsw * 8;
  const int qsw8 = ((g + (lr >> 1)) & 3) * 8;

  const short* ap0h = A  + (size_t)(bm*128 + w*16 + l2)*K1 + cof;
  const short* bp0h = Bt + (size_t)(bn*128 + w*16 + l2)*K1 + cof;
  const short* ap0a = FUSED ? (A2  + (size_t)(bm*128 + w*16 + l2)*K2 + cof) : nullptr;
  const short* bp0a = FUSED ? (Bt2 + (size_t)(bn*128 + w*16 + l2)*K2 + cof) : nullptr;

  // stage half-tile p into slot s (A: 2 gloads, B: 2 gloads)
  auto stage = [&](int s, int p){
    short* da = lds + s*4096 + w*512;
    short* db = lds + 12288 + s*4096 + w*512;
    if (FUSED && p >= NP1){
      size_t off = (size_t)(p - NP1)*32;
      gload16(ap0a + off, da);
      gload16(ap0a + (size_t)64*K2 + off, da + 2048);
      gload16(bp0a + off, db);
      gload16(bp0a + (size_t)64*K2 + off, db + 2048);
    } else {
      size_t off = (size_t)p*32;
      gload16(ap0h + off, da);
      gload16(ap0h + (size_t)64*K1 + off, da + 2048);
      gload16(bp0h + off, db);
      gload16(bp0h + (size_t)64*K1 + off, db + 2048);
    }
  };

#define LDA(s, mi) (*(const s16x8*)&lds[(s)*4096 + (wr*64 + (mi)*16 + lr)*32 + qsw8])
#define LDB(s, ni) (*(const s16x8*)&lds[12288 + (s)*4096 + (wc*64 + (ni)*16 + lr)*32 + qsw8])

  f32x4 acc[4][4] = {};

  // ---- prologue: stage half-tiles 0,1; certify 0 ----
  stage(0, 0);
  stage(1, 1);
  VMW4;
  PBAR;

  int sA = 0, sB = 1, sC = 2;
  for (int p = 0; p < NP; ++p){
    s16x8 a0=LDA(sA,0), a1=LDA(sA,1), a2=LDA(sA,2), a3=LDA(sA,3);
    s16x8 b0=LDB(sA,0), b1=LDB(sA,1), b2=LDB(sA,2), b3=LDB(sA,3);
    const bool st = (p + 2 < NP);
    if (st) stage(sC, p + 2);
    PBAR;
    PRIO1;
    acc[0][0]=mfma32(a0,b0,acc[0][0]); acc[0][1]=mfma32(a0,b1,acc[0][1]);
    acc[0][2]=mfma32(a0,b2,acc[0][2]); acc[0][3]=mfma32(a0,b3,acc[0][3]);
    acc[1][0]=mfma32(a1,b0,acc[1][0]); acc[1][1]=mfma32(a1,b1,acc[1][1]);
    acc[1][2]=mfma32(a1,b2,acc[1][2]); acc[1][3]=mfma32(a1,b3,acc[1][3]);
    acc[2][0]=mfma32(a2,b0,acc[2][0]); acc[2][1]=mfma32(a2,b1,acc[2][1]);
    acc[2][2]=mfma32(a2,b2,acc[2][2]); acc[2][3]=mfma32(a2,b3,acc[2][3]);
    acc[3][0]=mfma32(a3,b0,acc[3][0]); acc[3][1]=mfma32(a3,b1,acc[3][1]);
    acc[3][2]=mfma32(a3,b2,acc[3][2]); acc[3][3]=mfma32(a3,b3,acc[3][3]);
    PRIO0;
    if (st){ VMW4; } else if (p + 1 < NP){ VMW0; }
    PBAR;
    int t = sA; sA = sB; sB = sC; sC = t;   // rotate ring
  }
#undef LDA
#undef LDB

  if constexpr (QKVEPI){
    // ---- epilogue: LN(d=64)+reorg for q/k, transpose for v (R12) ----
#pragma unroll
    for (int a = 0; a < 4; ++a){
#pragma unroll
      for (int ni = 0; ni < 4; ++ni){
        const int col = wc*64 + ni*16 + lr;
        f32x4 v = acc[a][ni];
#pragma unroll
        for (int ii = 0; ii < 4; ++ii)
          lds[(wr*64 + a*16 + 4*g + ii)*130 + col] = f2bf(v[ii]);
      }
    }
    __syncthreads();
    const int part = (bn*128) >> 10;
    const int h0 = ((bn*128) & 1023) >> 6;
    const int rg = bm*128;
    const int b = rg >> 11;
    const int tok0 = rg & 2047;

    if (part < 2){
      short* dstbase = part ? kln : qln;
      const float sc = part ? 1.f : 0.04508422003f;
      const int row = tid >> 1, grp = tid & 1;
      const short* src = &lds[row*130 + grp*64];
      float s = 0.f, sq = 0.f;
#pragma unroll
      for (int i2 = 0; i2 < 8; ++i2){
        s16x8 u = *(const s16x8*)(src + i2*8);
#pragma unroll
        for (int j = 0; j < 8; ++j){ float fv = b2f(u[j]); s += fv; sq += fv*fv; }
      }
      const float mu = s * (1.f/64.f);
      const float var = sq * (1.f/64.f) - mu*mu;
      const float inv = rsqrtf(var + 1e-5f) * sc;
      const int bh = b*16 + h0 + grp;
      short* dst = dstbase + ((size_t)bh*Nc + tok0 + row)*64;
#pragma unroll
      for (int i2 = 0; i2 < 8; ++i2){
        s16x8 u = *(const s16x8*)(src + i2*8);
        s16x8 o;
#pragma unroll
        for (int j = 0; j < 8; ++j) o[j] = f2bf((b2f(u[j]) - mu) * inv);
        *(s16x8*)(dst + i2*8) = o;
      }
    } else {
      const int d = tid & 63, hh = (tid >> 6) & 1, half = tid >> 7;
      const int bh = b*16 + h0 + hh;
      short* dst = vtb + ((size_t)bh*64 + d)*Nc + tok0 + half*64;
#pragma unroll
      for (int i2 = 0; i2 < 8; ++i2){
        s16x8 o;
#pragma unroll
        for (int j = 0; j < 8; ++j)
          o[j] = lds[(half*64 + i2*8 + j)*130 + hh*64 + d];
        *(s16x8*)(dst + i2*8) = o;
      }
    }
    return;
  }

  // ---- normal epilogue: acc -> LDS (bf16) -> coalesced stores ----
#pragma unroll
  for (int a = 0; a < 4; ++a){
#pragma unroll
    for (int ni = 0; ni < 4; ++ni){
      const int col = wc*64 + ni*16 + lr;
      float bv = bias ? bias[bn*128 + col] : 0.f;
      if (FUSED && bias2) bv += bias2[bn*128 + col];
      f32x4 v = acc[a][ni];
#pragma unroll
      for (int ii = 0; ii < 4; ++ii){
        float val = v[ii] + bv;
        if constexpr (ACT) val = 0.5f*val*(1.f + erff(val*0.70710678118f));
        lds[(wr*64 + a*16 + 4*g + ii)*128 + col] = f2bf(val);
      }
    }
  }
  __syncthreads();
  const size_t crow0 = (size_t)bm * 128;
  const int ch = (tid & 15) * 8;
#pragma unroll
  for (int p = 0; p < 8; ++p){
    const int row = p*16 + (tid >> 4);
    *(s16x8*)&C[(crow0 + row)*N + bn*128 + ch] = *(const s16x8*)&lds[row*128 + ch];
  }
}

// ============================================================
// Flash attention (R8, unchanged): KVBLK=64 dbuf, 1 barrier/kt, fused 2x32.
// ============================================================
__global__ __launch_bounds__(256) void attn_kern(const short* __restrict__ qln, const short* __restrict__ kln,
                                                 const short* __restrict__ vtb, short* __restrict__ attnv){
  __shared__ short Ks[2][64*72];
  __shared__ short Vs[2][64*72];
  const int tid = threadIdx.x;
  const int bh = blockIdx.x >> 4, qt = blockIdx.x & 15;
  const int b = bh >> 4, h = bh & 15;
  const int w = tid >> 6, lane = tid & 63;
  const int lq = lane & 31, hi = lane >> 5;
  const int qrow = qt*128 + w*32 + lq;

  const short* qp = qln + ((size_t)bh*Nc + qrow)*64 + hi*8;
  s16x8 qf[4];
#pragma unroll
  for (int m = 0; m < 4; ++m) qf[m] = *(const s16x8*)(qp + m*16);

  f32x16 o0 = {0,0,0,0,0,0,0,0,0,0,0,0,0,0,0,0};
  f32x16 o1 = {0,0,0,0,0,0,0,0,0,0,0,0,0,0,0,0};
  float mrun = -INFINITY, l = 0.f;

  const int sr = tid >> 3;
  const int sc = (tid & 7) * 8;
  const short* kb0 = kln + (size_t)bh*Nc*64;
  const short* vb0 = vtb + (size_t)bh*64*Nc;

  s16x8 kr0, kr1, vr0, vr1;
  {
    kr0 = *(const s16x8*)(kb0 + (size_t)sr*64 + sc);
    kr1 = *(const s16x8*)(kb0 + (size_t)(32 + sr)*64 + sc);
    vr0 = *(const s16x8*)(vb0 + (size_t)sr*Nc + sc);
    vr1 = *(const s16x8*)(vb0 + (size_t)(32 + sr)*Nc + sc);
  }

  for (int kt = 0; kt < 32; ++kt){
    const int cur = kt & 1;
    *(s16x8*)&Ks[cur][sr*72 + sc]        = kr0;
    *(s16x8*)&Ks[cur][(32 + sr)*72 + sc] = kr1;
    *(s16x8*)&Vs[cur][sr*72 + sc]        = vr0;
    *(s16x8*)&Vs[cur][(32 + sr)*72 + sc] = vr1;
    __syncthreads();
    if (kt + 1 < 32){
      const short* kb = kb0 + (size_t)(kt+1)*64*64;
      const short* vb = vb0 + (kt+1)*64;
      kr0 = *(const s16x8*)(kb + (size_t)sr*64 + sc);
      kr1 = *(const s16x8*)(kb + (size_t)(32 + sr)*64 + sc);
      vr0 = *(const s16x8*)(vb + (size_t)sr*Nc + sc);
      vr1 = *(const s16x8*)(vb + (size_t)(32 + sr)*Nc + sc);
    }

    f32x16 st0 = {0,0,0,0,0,0,0,0,0,0,0,0,0,0,0,0};
    f32x16 st1 = {0,0,0,0,0,0,0,0,0,0,0,0,0,0,0,0};
#pragma unroll
    for (int m = 0; m < 4; ++m){
      s16x8 kf0 = *(const s16x8*)&Ks[cur][ lq      *72 + m*16 + hi*8];
      s16x8 kf1 = *(const s16x8*)&Ks[cur][(32 + lq)*72 + m*16 + hi*8];
      st0 = mfma3216(kf0, qf[m], st0);
      st1 = mfma3216(kf1, qf[m], st1);
    }

    float cmax = max3f(st0[0], st0[1], st0[2]);
    cmax = max3f(cmax, st0[3], st0[4]);   cmax = max3f(cmax, st0[5], st0[6]);
    cmax = max3f(cmax, st0[7], st0[8]);   cmax = max3f(cmax, st0[9], st0[10]);
    cmax = max3f(cmax, st0[11], st0[12]); cmax = max3f(cmax, st0[13], st0[14]);
    cmax = max3f(cmax, st0[15], st1[0]);  cmax = max3f(cmax, st1[1], st1[2]);
    cmax = max3f(cmax, st1[3], st1[4]);   cmax = max3f(cmax, st1[5], st1[6]);
    cmax = max3f(cmax, st1[7], st1[8]);   cmax = max3f(cmax, st1[9], st1[10]);
    cmax = max3f(cmax, st1[11], st1[12]); cmax = max3f(cmax, st1[13], st1[14]);
    cmax = fmaxf(cmax, st1[15]);
    cmax = fmaxf(cmax, __shfl_xor(cmax, 32));
    if (__any(cmax > mrun + 8.f)){
      float mnew = fmaxf(mrun, cmax);
      float fr = EXP2F(mrun - mnew);
      l *= fr;
#pragma unroll
      for (int r = 0; r < 16; ++r){ o0[r] *= fr; o1[r] *= fr; }
      mrun = mnew;
    }
    float p0[16], p1[16];
#pragma unroll
    for (int r = 0; r < 16; ++r){
      p0[r] = EXP2F(st0[r] - mrun); l += p0[r];
      p1[r] = EXP2F(st1[r] - mrun); l += p1[r];
    }

#pragma unroll
    for (int kc = 0; kc < 2; ++kc){
      const float* p = kc ? p1 : p0;
#pragma unroll
      for (int kh = 0; kh < 2; ++kh){
        int r0 = kh*8;
        unsigned wa = cvtpk(p[r0+0], p[r0+1]);
        unsigned wb = cvtpk(p[r0+4], p[r0+5]);
        unsigned wc2 = cvtpk(p[r0+2], p[r0+3]);
        unsigned wd = cvtpk(p[r0+6], p[r0+7]);
        uint2v s1 = pl32swap(wa, wb);
        uint2v s2 = pl32swap(wc2, wd);
        union { unsigned u[4]; s16x8 v; } pu;
        pu.u[0] = s1[0]; pu.u[1] = s2[0]; pu.u[2] = s1[1]; pu.u[3] = s2[1];
        s16x8 vf0 = *(const s16x8*)&Vs[cur][ lq      *72 + kc*32 + kh*16 + hi*8];
        s16x8 vf1 = *(const s16x8*)&Vs[cur][(32 + lq)*72 + kc*32 + kh*16 + hi*8];
        o0 = mfma3216(vf0, pu.v, o0);
        o1 = mfma3216(vf1, pu.v, o1);
      }
    }
  }

  l += __shfl_xor(l, 32);
  float inv = 1.f / l;
  short* orow = attnv + ((size_t)(b*Nc + qrow))*DIM + h*64;
#pragma unroll
  for (int r = 0; r < 16; r += 2){
    int dv = (r&3) + 8*(r>>2) + 4*hi;
    *(unsigned*)&orow[dv]      = cvtpk(o0[r]*inv, o0[r+1]*inv);
    *(unsigned*)&orow[32 + dv] = cvtpk(o1[r]*inv, o1[r+1]*inv);
  }
}

// ============================================================
// out = LayerNorm(s2) over 1024, fp32 out
// ============================================================
__global__ __launch_bounds__(256) void final_ln(const short* __restrict__ s2, float* __restrict__ out){
  __shared__ float red[16];
  int row = blockIdx.x, tid = threadIdx.x;
  size_t base = (size_t)row*DIM + tid*4;
  s16x4 a = *(const s16x4*)(s2 + base);
  float v[4]; float s = 0.f, sq = 0.f;
#pragma unroll
  for (int i = 0; i < 4; ++i){ v[i] = b2f(a[i]); s += v[i]; sq += v[i]*v[i]; }
#pragma unroll
  for (int m = 1; m < 64; m <<= 1){ s += __shfl_xor(s, m); sq += __shfl_xor(sq, m); }
  int wv = tid >> 6;
  if ((tid & 63) == 0){ red[wv] = s; red[8 + wv] = sq; }
  __syncthreads();
  if (tid == 0){
    float S = red[0] + red[1] + red[2] + red[3];
    float Q = red[8] + red[9] + red[10] + red[11];
    float mu = S * (1.f/1024.f);
    float var = Q * (1.f/1024.f) - mu*mu;
    red[12] = mu; red[13] = rsqrtf(var + 1e-5f);
  }
  __syncthreads();
  float mu = red[12], inv = red[13];
#pragma unroll
  for (int i = 0; i < 4; ++i) out[base + i] = (v[i] - mu) * inv;
}

// ============================================================
extern "C" void kernel_launch(void* const* d_in, const int* in_sizes, int n_in,
                              void* d_out, int out_size, void* d_ws, size_t ws_size,
                              hipStream_t stream){
  const float* x    = (const float*)d_in[0];
  const float* Wqkv = (const float*)d_in[1];
  const float* W1   = (const float*)d_in[2];
  const float* b1   = (const float*)d_in[3];
  const float* W2   = (const float*)d_in[4];
  const float* b2   = (const float*)d_in[5];
  const float* Wout = (const float*)d_in[6];
  const float* bout = (const float*)d_in[7];
  float* out = (float*)d_out;
  char* ws = (char*)d_ws;

  short* xb    = (short*)(ws + OFF_XB);
  short* wqkvt = (short*)(ws + OFF_WQKVT);
  short* w1t   = (short*)(ws + OFF_W1T);
  short* w2t   = (short*)(ws + OFF_W2T);
  short* woutt = (short*)(ws + OFF_WOUTT);
  short* qln   = (short*)(ws + OFF_QLN);
  short* kln   = (short*)(ws + OFF_KLN);
  short* vtb   = (short*)(ws + OFF_VT);
  short* attnv = (short*)(ws + OFF_ATTNV);
  short* hbuf  = (short*)(ws + OFF_H);
  short* s2    = (short*)(ws + OFF_S2);

  conv_x<<<4096, 256, 0, stream>>>(x, xb);
  transpose_conv<<<(DIM/32)*(D3/32),  256, 0, stream>>>(Wqkv, wqkvt, DIM, D3);
  transpose_conv<<<(DIM/32)*(MLP/32), 256, 0, stream>>>(W1, w1t, DIM, MLP);
  transpose_conv<<<(MLP/32)*(DIM/32), 256, 0, stream>>>(W2, w2t, MLP, DIM);
  transpose_conv<<<(DIM/32)*(DIM/32), 256, 0, stream>>>(Wout, woutt, DIM, DIM);

  // qkv gemm with fused q/k-LN + head-reorg + V-transpose epilogue
  gemmCF<0,0,1><<<(Tc/128)*(D3/128), 256, 0, stream>>>(xb, xb, wqkvt, wqkvt, nullptr,
                                                       nullptr, nullptr, Tc, D3, DIM, DIM,
                                                       qln, kln, vtb);
  attn_kern<<<64*16, 256, 0, stream>>>(qln, kln, vtb, attnv);

  gemmCF<1,0,0><<<(Tc/128)*(MLP/128), 256, 0, stream>>>(xb, xb, w1t, w1t, hbuf,
                                                        b1, nullptr, Tc, MLP, DIM, DIM,
                                                        nullptr, nullptr, nullptr);
  // fused: s2 = hbuf@W2 + attnv@Wout + b2 + bout   (K = 4096 + 1024)
  gemmCF<0,1,0><<<(Tc/128)*(DIM/128), 256, 0, stream>>>(hbuf, attnv, w2t, woutt, s2,
                                                        b2, bout, Tc, DIM, MLP, DIM,
                                                        nullptr, nullptr, nullptr);

  final_ln<<<Tc, 256, 0, stream>>>(s2, out);
}

// Round 14
// 415.635 us; speedup vs baseline: 1.3796x; 1.3796x over previous
//
#include <hip/hip_runtime.h>

typedef __attribute__((ext_vector_type(8))) short s16x8;
typedef __attribute__((ext_vector_type(4))) short s16x4;
typedef __attribute__((ext_vector_type(4))) float f32x4;
typedef __attribute__((ext_vector_type(16))) float f32x16;
typedef __attribute__((ext_vector_type(2))) unsigned uint2v;

#define DEVINL __device__ __forceinline__

// ---------- bf16 helpers ----------
DEVINL float b2f(short u){ return __uint_as_float(((unsigned)(unsigned short)u) << 16); }
DEVINL short f2bf(float f){
  unsigned u = __float_as_uint(f);
  u += 0x7fffu + ((u >> 16) & 1u);
  return (short)(u >> 16);
}
DEVINL unsigned cvtpk(float lo, float hi){
  unsigned r;
  asm("v_cvt_pk_bf16_f32 %0, %1, %2" : "=v"(r) : "v"(lo), "v"(hi));
  return r;
}
DEVINL float max3f(float a, float b, float c){
  float r; asm("v_max3_f32 %0, %1, %2, %3" : "=v"(r) : "v"(a), "v"(b), "v"(c)); return r;
}

#if __has_builtin(__builtin_amdgcn_exp2f)
#define EXP2F __builtin_amdgcn_exp2f
#else
#define EXP2F exp2f
#endif

// ---------- MFMA wrappers ----------
DEVINL f32x4 mfma32(s16x8 a, s16x8 b, f32x4 c){
  return __builtin_amdgcn_mfma_f32_16x16x32_bf16(a, b, c, 0, 0, 0);
}
DEVINL f32x16 mfma3216(s16x8 a, s16x8 b, f32x16 c){
  return __builtin_amdgcn_mfma_f32_32x32x16_bf16(a, b, c, 0, 0, 0);
}

DEVINL uint2v pl32swap(unsigned a, unsigned b){
#if __has_builtin(__builtin_amdgcn_permlane32_swap)
  return __builtin_amdgcn_permlane32_swap(a, b, false, false);
#else
  asm volatile("v_permlane32_swap_b32 %0, %1" : "+v"(a), "+v"(b));
  uint2v r; r[0] = a; r[1] = b; return r;
#endif
}

// ---------- async global->LDS (width 16) ----------
typedef const unsigned __attribute__((address_space(1)))* gas1;
typedef unsigned __attribute__((address_space(3)))* las3;
DEVINL void gload16(const short* g, short* l){
  __builtin_amdgcn_global_load_lds((gas1)g, (las3)l, 16, 0, 0);
}

// ---------- sync primitives ----------
#define CFENCE asm volatile("" ::: "memory")
#define PBAR  do{ CFENCE; __builtin_amdgcn_sched_barrier(0); __builtin_amdgcn_s_barrier(); \
                  __builtin_amdgcn_sched_barrier(0); CFENCE; }while(0)
#define VMW8 asm volatile("s_waitcnt vmcnt(8)" ::: "memory")
#define VMW4 asm volatile("s_waitcnt vmcnt(4)" ::: "memory")
#define VMW0 asm volatile("s_waitcnt vmcnt(0)" ::: "memory")
#define PRIO1 __builtin_amdgcn_s_setprio(1)
#define PRIO0 __builtin_amdgcn_s_setprio(0)

// ---------- problem constants ----------
static const int Bc   = 4;
static const int Nc   = 2048;
static const int DIM  = 1024;
static const int Tc   = Bc * Nc;      // 8192 tokens
static const int MLP  = 4096;
static const int D3   = 3072;

// ---------- ws layout (bytes) ----------
static const size_t OFF_XB    = 0;
static const size_t OFF_WQKVT = OFF_XB    + 16777216;
static const size_t OFF_W1T   = OFF_WQKVT + 6291456;
static const size_t OFF_W2T   = OFF_W1T   + 8388608;
static const size_t OFF_WOUTT = OFF_W2T   + 8388608;
static const size_t OFF_QKV   = OFF_WOUTT + 2097152;   // (not materialized; reused by hbuf)
static const size_t OFF_QLN   = OFF_QKV   + 50331648;
static const size_t OFF_KLN   = OFF_QLN   + 16777216;
static const size_t OFF_VT    = OFF_KLN   + 16777216;
static const size_t OFF_ATTNV = OFF_VT    + 16777216;
static const size_t OFF_H     = OFF_QKV;   // hbuf over dead qkv+qln (after attn)
static const size_t OFF_S2    = OFF_KLN;   // fused MLP2+Wout output over dead kln

// ============================================================
// x fp32 -> bf16
// ============================================================
__global__ __launch_bounds__(256) void conv_x(const float* __restrict__ x, short* __restrict__ xb){
  size_t i = ((size_t)blockIdx.x * 256 + threadIdx.x) * 8;
  f32x4 v0 = *(const f32x4*)(x + i);
  f32x4 v1 = *(const f32x4*)(x + i + 4);
  s16x8 o;
#pragma unroll
  for (int j = 0; j < 4; ++j){ o[j] = f2bf(v0[j]); o[4+j] = f2bf(v1[j]); }
  *(s16x8*)(xb + i) = o;
}

// ============================================================
// W[K][N] fp32 -> Wt[N][K] bf16
// ============================================================
__global__ __launch_bounds__(256) void transpose_conv(const float* __restrict__ W, short* __restrict__ Wt,
                                                      int K, int N){
  __shared__ float tile[32][33];
  int ntx = N >> 5;
  int tx = blockIdx.x % ntx, ty = blockIdx.x / ntx;
  int r = threadIdx.x >> 3, c = (threadIdx.x & 7) * 4;
  f32x4 v = *(const f32x4*)(W + (size_t)(ty*32 + r)*N + tx*32 + c);
  tile[r][c] = v[0]; tile[r][c+1] = v[1]; tile[r][c+2] = v[2]; tile[r][c+3] = v[3];
  __syncthreads();
  s16x4 o;
#pragma unroll
  for (int j = 0; j < 4; ++j) o[j] = f2bf(tile[c+j][r]);
  *(s16x4*)(Wt + (size_t)(tx*32 + r)*K + ty*32 + c) = o;
}

// ============================================================
// gemmCF (R7/R8 structure; R12 best): 128x128, 4 waves, 64KB LDS, 2 blocks/CU,
// counted-vmcnt ring, conflict-free k-group swizzle, LDS-staged epilogue.
// FUSED: K-range [0,K1) reads A/Bt, [K1,K1+K2) reads A2/Bt2.
// QKVEPI: q/k LayerNorm(d=64) + head-reorg (qln/kln) or V-transpose (vtb)
// directly from the LDS tile. Tile is LN-closed: 128 cols = 2 heads x d=64,
// one part; 128 rows = tokens of one batch. Stride 130 -> near-conflict-free
// column reads; LN row reads 2-way (free, m136).
// ============================================================
template<int ACT, int FUSED, int QKVEPI>
__global__ __launch_bounds__(256, 2) void gemmCF(const short* __restrict__ A, const short* __restrict__ A2,
                                                 const short* __restrict__ Bt, const short* __restrict__ Bt2,
                                                 short* __restrict__ C,
                                                 const float* __restrict__ bias, const float* __restrict__ bias2,
                                                 int M, int N, int K1, int K2,
                                                 short* __restrict__ qln, short* __restrict__ kln,
                                                 short* __restrict__ vtb){
  __shared__ short lds[32768];

  const int tid = threadIdx.x;
  const int w = tid >> 6, lane = tid & 63;
  const int lr = lane & 15, g = lane >> 4;
  const int wr = w >> 1, wc = w & 1;
  const int NT1 = K1 >> 6;
  const int NT = NT1 + (FUSED ? (K2 >> 6) : 0);
  const int NIT = NT >> 1;

  const int nbn = N >> 7;
  const int cpx = gridDim.x >> 3;
  const int bid = (int)blockIdx.x;
  const int sw = (bid & 7)*cpx + (bid >> 3);
  const int nbn8 = nbn >> 3;
  const int T8 = sw >> 6, t64 = sw & 63;
  const int bm = (T8 / nbn8)*8 + (t64 >> 3);
  const int bn = (T8 % nbn8)*8 + (t64 & 7);

  const int l2 = lane >> 2;
  const int gsw = ((lane & 3) - ((lane >> 3) & 3)) & 3;
  const int cof = gsw * 8;
  const int qsw8 = ((g + (lr >> 1)) & 3) * 8;

  const short* ap0h = A  + (size_t)(bm*128 + w*16 + l2)*K1 + cof;
  const short* bp0h = Bt + (size_t)(bn*128 + w*16 + l2)*K1 + cof;
  const short* ap0a = FUSED ? (A2  + (size_t)(bm*128 + w*16 + l2)*K2 + cof) : nullptr;
  const short* bp0a = FUSED ? (Bt2 + (size_t)(bn*128 + w*16 + l2)*K2 + cof) : nullptr;

  auto stA = [&](int s, int T_, int kk){
    short* d0 = lds + s*4096 + w*512;
    if (FUSED && T_ >= NT1){
      size_t off = (size_t)(T_ - NT1)*64 + kk*32;
      gload16(ap0a + off, d0);
      gload16(ap0a + (size_t)64*K2 + off, d0 + 2048);
    } else {
      size_t off = (size_t)T_*64 + kk*32;
      gload16(ap0h + off, d0);
      gload16(ap0h + (size_t)64*K1 + off, d0 + 2048);
    }
  };
  auto stB = [&](int s, int T_, int kk){
    short* d0 = lds + 16384 + s*4096 + w*512;
    if (FUSED && T_ >= NT1){
      size_t off = (size_t)(T_ - NT1)*64 + kk*32;
      gload16(bp0a + off, d0);
      gload16(bp0a + (size_t)64*K2 + off, d0 + 2048);
    } else {
      size_t off = (size_t)T_*64 + kk*32;
      gload16(bp0h + off, d0);
      gload16(bp0h + (size_t)64*K1 + off, d0 + 2048);
    }
  };

#define LDA(s, mi) (*(const s16x8*)&lds[(s)*4096 + (wr*64 + (mi)*16 + lr)*32 + qsw8])
#define LDB(s, ni) (*(const s16x8*)&lds[16384 + (s)*4096 + (wc*64 + (ni)*16 + lr)*32 + qsw8])

  f32x4 acc[4][4] = {};
#define MM(ai, r) \
  acc[r][0]=mfma32(ai,b0,acc[r][0]); acc[r][1]=mfma32(ai,b1,acc[r][1]); \
  acc[r][2]=mfma32(ai,b2,acc[r][2]); acc[r][3]=mfma32(ai,b3,acc[r][3]);
#define RD(s) s16x8 a0=LDA(s,0),a1=LDA(s,1),a2=LDA(s,2),a3=LDA(s,3), \
                    b0=LDB(s,0),b1=LDB(s,1),b2=LDB(s,2),b3=LDB(s,3);
#define MM16 MM(a0,0) MM(a1,1) MM(a2,2) MM(a3,3)

  stA(0,0,0); stB(0,0,0);
  stA(1,0,1); stB(1,0,1);
  stA(2,1,0); stB(2,1,0);
  VMW8;
  PBAR;

  for (int i = 0; i < NIT; ++i){
    const int t = i << 1;
    const bool more = (i + 1 < NIT);
    {
      RD(0)
      stA(3, t+1, 1); stB(3, t+1, 1);
      PBAR; PRIO1; MM16 PRIO0;
      VMW8;
      PBAR;
    }
    {
      RD(1)
      if (more){ stA(0, t+2, 0); stB(0, t+2, 0); }
      PBAR; PRIO1; MM16 PRIO0;
      if (more){ VMW8; } else { VMW4; }
      PBAR;
    }
    {
      RD(2)
      if (more){ stA(1, t+2, 1); stB(1, t+2, 1); }
      PBAR; PRIO1; MM16 PRIO0;
      if (more){ VMW8; } else { VMW0; }
      PBAR;
    }
    {
      RD(3)
      if (more){ stA(2, t+3, 0); stB(2, t+3, 0); }
      PBAR; PRIO1; MM16 PRIO0;
      if (more){ VMW8; }
      PBAR;
    }
  }
#undef MM
#undef RD
#undef MM16
#undef LDA
#undef LDB

  if constexpr (QKVEPI){
    // ---- epilogue: LN(d=64)+reorg for q/k, transpose for v ----
#pragma unroll
    for (int a = 0; a < 4; ++a){
#pragma unroll
      for (int ni = 0; ni < 4; ++ni){
        const int col = wc*64 + ni*16 + lr;
        f32x4 v = acc[a][ni];
#pragma unroll
        for (int ii = 0; ii < 4; ++ii)
          lds[(wr*64 + a*16 + 4*g + ii)*130 + col] = f2bf(v[ii]);
      }
    }
    __syncthreads();
    const int part = (bn*128) >> 10;          // 0=q, 1=k, 2=v
    const int h0 = ((bn*128) & 1023) >> 6;    // first head in tile
    const int rg = bm*128;
    const int b = rg >> 11;
    const int tok0 = rg & 2047;

    if (part < 2){
      short* dstbase = part ? kln : qln;
      const float sc = part ? 1.f : 0.04508422003f;   // q: dim^-0.5 * log2(e)
      const int row = tid >> 1, grp = tid & 1;
      const short* src = &lds[row*130 + grp*64];
      float s = 0.f, sq = 0.f;
#pragma unroll
      for (int i2 = 0; i2 < 8; ++i2){
        s16x8 u = *(const s16x8*)(src + i2*8);
#pragma unroll
        for (int j = 0; j < 8; ++j){ float fv = b2f(u[j]); s += fv; sq += fv*fv; }
      }
      const float mu = s * (1.f/64.f);
      const float var = sq * (1.f/64.f) - mu*mu;
      const float inv = rsqrtf(var + 1e-5f) * sc;
      const int bh = b*16 + h0 + grp;
      short* dst = dstbase + ((size_t)bh*Nc + tok0 + row)*64;
#pragma unroll
      for (int i2 = 0; i2 < 8; ++i2){
        s16x8 u = *(const s16x8*)(src + i2*8);
        s16x8 o;
#pragma unroll
        for (int j = 0; j < 8; ++j) o[j] = f2bf((b2f(u[j]) - mu) * inv);
        *(s16x8*)(dst + i2*8) = o;
      }
    } else {
      // v: write vtb[bh][d][token]
      const int d = tid & 63, hh = (tid >> 6) & 1, half = tid >> 7;
      const int bh = b*16 + h0 + hh;
      short* dst = vtb + ((size_t)bh*64 + d)*Nc + tok0 + half*64;
#pragma unroll
      for (int i2 = 0; i2 < 8; ++i2){
        s16x8 o;
#pragma unroll
        for (int j = 0; j < 8; ++j)
          o[j] = lds[(half*64 + i2*8 + j)*130 + hh*64 + d];
        *(s16x8*)(dst + i2*8) = o;
      }
    }
    return;
  }

  // ---- normal epilogue: acc -> LDS (bf16) -> coalesced stores ----
#pragma unroll
  for (int a = 0; a < 4; ++a){
#pragma unroll
    for (int ni = 0; ni < 4; ++ni){
      const int col = wc*64 + ni*16 + lr;
      float bv = bias ? bias[bn*128 + col] : 0.f;
      if (FUSED && bias2) bv += bias2[bn*128 + col];
      f32x4 v = acc[a][ni];
#pragma unroll
      for (int ii = 0; ii < 4; ++ii){
        float val = v[ii] + bv;
        if constexpr (ACT) val = 0.5f*val*(1.f + erff(val*0.70710678118f));
        lds[(wr*64 + a*16 + 4*g + ii)*128 + col] = f2bf(val);
      }
    }
  }
  __syncthreads();
  const size_t crow0 = (size_t)bm * 128;
  const int ch = (tid & 15) * 8;
#pragma unroll
  for (int p = 0; p < 8; ++p){
    const int row = p*16 + (tid >> 4);
    *(s16x8*)&C[(crow0 + row)*N + bn*128 + ch] = *(const s16x8*)&lds[row*128 + ch];
  }
}

// ============================================================
// Flash attention (R8): KVBLK=64 dbuf, 1 barrier/kt, fused 2x32-key,
// swapped QK^T (32x32), exp2-domain softmax, defer-max, cvt_pk+permlane.
// ============================================================
__global__ __launch_bounds__(256) void attn_kern(const short* __restrict__ qln, const short* __restrict__ kln,
                                                 const short* __restrict__ vtb, short* __restrict__ attnv){
  __shared__ short Ks[2][64*72];
  __shared__ short Vs[2][64*72];
  const int tid = threadIdx.x;
  const int bh = blockIdx.x >> 4, qt = blockIdx.x & 15;
  const int b = bh >> 4, h = bh & 15;
  const int w = tid >> 6, lane = tid & 63;
  const int lq = lane & 31, hi = lane >> 5;
  const int qrow = qt*128 + w*32 + lq;

  const short* qp = qln + ((size_t)bh*Nc + qrow)*64 + hi*8;
  s16x8 qf[4];
#pragma unroll
  for (int m = 0; m < 4; ++m) qf[m] = *(const s16x8*)(qp + m*16);

  f32x16 o0 = {0,0,0,0,0,0,0,0,0,0,0,0,0,0,0,0};
  f32x16 o1 = {0,0,0,0,0,0,0,0,0,0,0,0,0,0,0,0};
  float mrun = -INFINITY, l = 0.f;

  const int sr = tid >> 3;
  const int sc = (tid & 7) * 8;
  const short* kb0 = kln + (size_t)bh*Nc*64;
  const short* vb0 = vtb + (size_t)bh*64*Nc;

  s16x8 kr0, kr1, vr0, vr1;
  {
    kr0 = *(const s16x8*)(kb0 + (size_t)sr*64 + sc);
    kr1 = *(const s16x8*)(kb0 + (size_t)(32 + sr)*64 + sc);
    vr0 = *(const s16x8*)(vb0 + (size_t)sr*Nc + sc);
    vr1 = *(const s16x8*)(vb0 + (size_t)(32 + sr)*Nc + sc);
  }

  for (int kt = 0; kt < 32; ++kt){
    const int cur = kt & 1;
    *(s16x8*)&Ks[cur][sr*72 + sc]        = kr0;
    *(s16x8*)&Ks[cur][(32 + sr)*72 + sc] = kr1;
    *(s16x8*)&Vs[cur][sr*72 + sc]        = vr0;
    *(s16x8*)&Vs[cur][(32 + sr)*72 + sc] = vr1;
    __syncthreads();
    if (kt + 1 < 32){
      const short* kb = kb0 + (size_t)(kt+1)*64*64;
      const short* vb = vb0 + (kt+1)*64;
      kr0 = *(const s16x8*)(kb + (size_t)sr*64 + sc);
      kr1 = *(const s16x8*)(kb + (size_t)(32 + sr)*64 + sc);
      vr0 = *(const s16x8*)(vb + (size_t)sr*Nc + sc);
      vr1 = *(const s16x8*)(vb + (size_t)(32 + sr)*Nc + sc);
    }

    f32x16 st0 = {0,0,0,0,0,0,0,0,0,0,0,0,0,0,0,0};
    f32x16 st1 = {0,0,0,0,0,0,0,0,0,0,0,0,0,0,0,0};
#pragma unroll
    for (int m = 0; m < 4; ++m){
      s16x8 kf0 = *(const s16x8*)&Ks[cur][ lq      *72 + m*16 + hi*8];
      s16x8 kf1 = *(const s16x8*)&Ks[cur][(32 + lq)*72 + m*16 + hi*8];
      st0 = mfma3216(kf0, qf[m], st0);
      st1 = mfma3216(kf1, qf[m], st1);
    }

    float cmax = max3f(st0[0], st0[1], st0[2]);
    cmax = max3f(cmax, st0[3], st0[4]);   cmax = max3f(cmax, st0[5], st0[6]);
    cmax = max3f(cmax, st0[7], st0[8]);   cmax = max3f(cmax, st0[9], st0[10]);
    cmax = max3f(cmax, st0[11], st0[12]); cmax = max3f(cmax, st0[13], st0[14]);
    cmax = max3f(cmax, st0[15], st1[0]);  cmax = max3f(cmax, st1[1], st1[2]);
    cmax = max3f(cmax, st1[3], st1[4]);   cmax = max3f(cmax, st1[5], st1[6]);
    cmax = max3f(cmax, st1[7], st1[8]);   cmax = max3f(cmax, st1[9], st1[10]);
    cmax = max3f(cmax, st1[11], st1[12]); cmax = max3f(cmax, st1[13], st1[14]);
    cmax = fmaxf(cmax, st1[15]);
    cmax = fmaxf(cmax, __shfl_xor(cmax, 32));
    if (__any(cmax > mrun + 8.f)){
      float mnew = fmaxf(mrun, cmax);
      float fr = EXP2F(mrun - mnew);
      l *= fr;
#pragma unroll
      for (int r = 0; r < 16; ++r){ o0[r] *= fr; o1[r] *= fr; }
      mrun = mnew;
    }
    float p0[16], p1[16];
#pragma unroll
    for (int r = 0; r < 16; ++r){
      p0[r] = EXP2F(st0[r] - mrun); l += p0[r];
      p1[r] = EXP2F(st1[r] - mrun); l += p1[r];
    }

#pragma unroll
    for (int kc = 0; kc < 2; ++kc){
      const float* p = kc ? p1 : p0;
#pragma unroll
      for (int kh = 0; kh < 2; ++kh){
        int r0 = kh*8;
        unsigned wa = cvtpk(p[r0+0], p[r0+1]);
        unsigned wb = cvtpk(p[r0+4], p[r0+5]);
        unsigned wc2 = cvtpk(p[r0+2], p[r0+3]);
        unsigned wd = cvtpk(p[r0+6], p[r0+7]);
        uint2v s1 = pl32swap(wa, wb);
        uint2v s2 = pl32swap(wc2, wd);
        union { unsigned u[4]; s16x8 v; } pu;
        pu.u[0] = s1[0]; pu.u[1] = s2[0]; pu.u[2] = s1[1]; pu.u[3] = s2[1];
        s16x8 vf0 = *(const s16x8*)&Vs[cur][ lq      *72 + kc*32 + kh*16 + hi*8];
        s16x8 vf1 = *(const s16x8*)&Vs[cur][(32 + lq)*72 + kc*32 + kh*16 + hi*8];
        o0 = mfma3216(vf0, pu.v, o0);
        o1 = mfma3216(vf1, pu.v, o1);
      }
    }
  }

  l += __shfl_xor(l, 32);
  float inv = 1.f / l;
  short* orow = attnv + ((size_t)(b*Nc + qrow))*DIM + h*64;
#pragma unroll
  for (int r = 0; r < 16; r += 2){
    int dv = (r&3) + 8*(r>>2) + 4*hi;
    *(unsigned*)&orow[dv]      = cvtpk(o0[r]*inv, o0[r+1]*inv);
    *(unsigned*)&orow[32 + dv] = cvtpk(o1[r]*inv, o1[r+1]*inv);
  }
}

// ============================================================
// out = LayerNorm(s2) over 1024, fp32 out
// ============================================================
__global__ __launch_bounds__(256) void final_ln(const short* __restrict__ s2, float* __restrict__ out){
  __shared__ float red[16];
  int row = blockIdx.x, tid = threadIdx.x;
  size_t base = (size_t)row*DIM + tid*4;
  s16x4 a = *(const s16x4*)(s2 + base);
  float v[4]; float s = 0.f, sq = 0.f;
#pragma unroll
  for (int i = 0; i < 4; ++i){ v[i] = b2f(a[i]); s += v[i]; sq += v[i]*v[i]; }
#pragma unroll
  for (int m = 1; m < 64; m <<= 1){ s += __shfl_xor(s, m); sq += __shfl_xor(sq, m); }
  int wv = tid >> 6;
  if ((tid & 63) == 0){ red[wv] = s; red[8 + wv] = sq; }
  __syncthreads();
  if (tid == 0){
    float S = red[0] + red[1] + red[2] + red[3];
    float Q = red[8] + red[9] + red[10] + red[11];
    float mu = S * (1.f/1024.f);
    float var = Q * (1.f/1024.f) - mu*mu;
    red[12] = mu; red[13] = rsqrtf(var + 1e-5f);
  }
  __syncthreads();
  float mu = red[12], inv = red[13];
#pragma unroll
  for (int i = 0; i < 4; ++i) out[base + i] = (v[i] - mu) * inv;
}

// ============================================================
extern "C" void kernel_launch(void* const* d_in, const int* in_sizes, int n_in,
                              void* d_out, int out_size, void* d_ws, size_t ws_size,
                              hipStream_t stream){
  const float* x    = (const float*)d_in[0];
  const float* Wqkv = (const float*)d_in[1];
  const float* W1   = (const float*)d_in[2];
  const float* b1   = (const float*)d_in[3];
  const float* W2   = (const float*)d_in[4];
  const float* b2   = (const float*)d_in[5];
  const float* Wout = (const float*)d_in[6];
  const float* bout = (const float*)d_in[7];
  float* out = (float*)d_out;
  char* ws = (char*)d_ws;

  short* xb    = (short*)(ws + OFF_XB);
  short* wqkvt = (short*)(ws + OFF_WQKVT);
  short* w1t   = (short*)(ws + OFF_W1T);
  short* w2t   = (short*)(ws + OFF_W2T);
  short* woutt = (short*)(ws + OFF_WOUTT);
  short* qln   = (short*)(ws + OFF_QLN);
  short* kln   = (short*)(ws + OFF_KLN);
  short* vtb   = (short*)(ws + OFF_VT);
  short* attnv = (short*)(ws + OFF_ATTNV);
  short* hbuf  = (short*)(ws + OFF_H);
  short* s2    = (short*)(ws + OFF_S2);

  conv_x<<<4096, 256, 0, stream>>>(x, xb);
  transpose_conv<<<(DIM/32)*(D3/32),  256, 0, stream>>>(Wqkv, wqkvt, DIM, D3);
  transpose_conv<<<(DIM/32)*(MLP/32), 256, 0, stream>>>(W1, w1t, DIM, MLP);
  transpose_conv<<<(MLP/32)*(DIM/32), 256, 0, stream>>>(W2, w2t, MLP, DIM);
  transpose_conv<<<(DIM/32)*(DIM/32), 256, 0, stream>>>(Wout, woutt, DIM, DIM);

  // qkv gemm with fused q/k-LN + head-reorg + V-transpose epilogue (no qkv buffer)
  gemmCF<0,0,1><<<(Tc/128)*(D3/128), 256, 0, stream>>>(xb, xb, wqkvt, wqkvt, nullptr,
                                                       nullptr, nullptr, Tc, D3, DIM, DIM,
                                                       qln, kln, vtb);
  attn_kern<<<64*16, 256, 0, stream>>>(qln, kln, vtb, attnv);

  gemmCF<1,0,0><<<(Tc/128)*(MLP/128), 256, 0, stream>>>(xb, xb, w1t, w1t, hbuf,
                                                        b1, nullptr, Tc, MLP, DIM, DIM,
                                                        nullptr, nullptr, nullptr);
  // fused: s2 = hbuf@W2 + attnv@Wout + b2 + bout   (K = 4096 + 1024)
  gemmCF<0,1,0><<<(Tc/128)*(DIM/128), 256, 0, stream>>>(hbuf, attnv, w2t, woutt, s2,
                                                        b2, bout, Tc, DIM, MLP, DIM,
                                                        nullptr, nullptr, nullptr);

  final_ln<<<Tc, 256, 0, stream>>>(s2, out);
}

// Round 15
// 405.712 us; speedup vs baseline: 1.4134x; 1.0245x over previous
//
#include <hip/hip_runtime.h>

typedef __attribute__((ext_vector_type(8))) short s16x8;
typedef __attribute__((ext_vector_type(4))) short s16x4;
typedef __attribute__((ext_vector_type(4))) float f32x4;
typedef __attribute__((ext_vector_type(16))) float f32x16;
typedef __attribute__((ext_vector_type(2))) unsigned uint2v;

#define DEVINL __device__ __forceinline__

// ---------- bf16 helpers ----------
DEVINL float b2f(short u){ return __uint_as_float(((unsigned)(unsigned short)u) << 16); }
DEVINL short f2bf(float f){
  unsigned u = __float_as_uint(f);
  u += 0x7fffu + ((u >> 16) & 1u);
  return (short)(u >> 16);
}
DEVINL unsigned cvtpk(float lo, float hi){
  unsigned r;
  asm("v_cvt_pk_bf16_f32 %0, %1, %2" : "=v"(r) : "v"(lo), "v"(hi));
  return r;
}
DEVINL float max3f(float a, float b, float c){
  float r; asm("v_max3_f32 %0, %1, %2, %3" : "=v"(r) : "v"(a), "v"(b), "v"(c)); return r;
}

#if __has_builtin(__builtin_amdgcn_exp2f)
#define EXP2F __builtin_amdgcn_exp2f
#else
#define EXP2F exp2f
#endif

// ---------- MFMA wrappers ----------
DEVINL f32x4 mfma32(s16x8 a, s16x8 b, f32x4 c){
  return __builtin_amdgcn_mfma_f32_16x16x32_bf16(a, b, c, 0, 0, 0);
}
DEVINL f32x16 mfma3216(s16x8 a, s16x8 b, f32x16 c){
  return __builtin_amdgcn_mfma_f32_32x32x16_bf16(a, b, c, 0, 0, 0);
}

DEVINL uint2v pl32swap(unsigned a, unsigned b){
#if __has_builtin(__builtin_amdgcn_permlane32_swap)
  return __builtin_amdgcn_permlane32_swap(a, b, false, false);
#else
  asm volatile("v_permlane32_swap_b32 %0, %1" : "+v"(a), "+v"(b));
  uint2v r; r[0] = a; r[1] = b; return r;
#endif
}

// ---------- async global->LDS (width 16) ----------
typedef const unsigned __attribute__((address_space(1)))* gas1;
typedef unsigned __attribute__((address_space(3)))* las3;
DEVINL void gload16(const short* g, short* l){
  __builtin_amdgcn_global_load_lds((gas1)g, (las3)l, 16, 0, 0);
}

// ---------- sync primitives ----------
#define CFENCE asm volatile("" ::: "memory")
#define PBAR  do{ CFENCE; __builtin_amdgcn_sched_barrier(0); __builtin_amdgcn_s_barrier(); \
                  __builtin_amdgcn_sched_barrier(0); CFENCE; }while(0)
#define VMW8 asm volatile("s_waitcnt vmcnt(8)" ::: "memory")
#define VMW4 asm volatile("s_waitcnt vmcnt(4)" ::: "memory")
#define VMW0 asm volatile("s_waitcnt vmcnt(0)" ::: "memory")
#define PRIO1 __builtin_amdgcn_s_setprio(1)
#define PRIO0 __builtin_amdgcn_s_setprio(0)

// ---------- problem constants ----------
static const int Bc   = 4;
static const int Nc   = 2048;
static const int DIM  = 1024;
static const int Tc   = Bc * Nc;      // 8192 tokens
static const int MLP  = 4096;
static const int D3   = 3072;

// ---------- ws layout (bytes) ----------
static const size_t OFF_XB    = 0;
static const size_t OFF_WQKVT = OFF_XB    + 16777216;
static const size_t OFF_W1T   = OFF_WQKVT + 6291456;
static const size_t OFF_W2T   = OFF_W1T   + 8388608;
static const size_t OFF_WOUTT = OFF_W2T   + 8388608;
static const size_t OFF_QKV   = OFF_WOUTT + 2097152;   // (not materialized; reused by hbuf)
static const size_t OFF_QLN   = OFF_QKV   + 50331648;
static const size_t OFF_KLN   = OFF_QLN   + 16777216;
static const size_t OFF_VT    = OFF_KLN   + 16777216;
static const size_t OFF_ATTNV = OFF_VT    + 16777216;
static const size_t OFF_H     = OFF_QKV;   // hbuf over dead qkv+qln (after attn)
static const size_t OFF_S2    = OFF_KLN;   // fused MLP2+Wout output over dead kln

// ============================================================
// prep_all (R15): ONE launch replacing conv_x + 4x transpose_conv.
// Block ranges (blockIdx-uniform branches; __syncthreads legal):
//   [0, 4096)            : x fp32 -> bf16 (8 elems/thread)
//   [4096, 7168)         : Wqkv  [1024][3072] -> wqkvt  [3072][1024]
//   [7168, 11264)        : W1    [1024][4096] -> w1t    [4096][1024]
//   [11264, 15360)       : W2    [4096][1024] -> w2t    [1024][4096]
//   [15360, 16384)       : Wout  [1024][1024] -> woutt  [1024][1024]
// ============================================================
DEVINL void transp_body(const float* __restrict__ W, short* __restrict__ Wt,
                        int K, int N, int bid){
  __shared__ float tile[32][33];
  int ntx = N >> 5;
  int tx = bid % ntx, ty = bid / ntx;
  int r = threadIdx.x >> 3, c = (threadIdx.x & 7) * 4;
  f32x4 v = *(const f32x4*)(W + (size_t)(ty*32 + r)*N + tx*32 + c);
  tile[r][c] = v[0]; tile[r][c+1] = v[1]; tile[r][c+2] = v[2]; tile[r][c+3] = v[3];
  __syncthreads();
  s16x4 o;
#pragma unroll
  for (int j = 0; j < 4; ++j) o[j] = f2bf(tile[c+j][r]);
  *(s16x4*)(Wt + (size_t)(tx*32 + r)*K + ty*32 + c) = o;
}

__global__ __launch_bounds__(256) void prep_all(const float* __restrict__ x, short* __restrict__ xb,
                                                const float* __restrict__ Wqkv, short* __restrict__ wqkvt,
                                                const float* __restrict__ W1, short* __restrict__ w1t,
                                                const float* __restrict__ W2, short* __restrict__ w2t,
                                                const float* __restrict__ Wout, short* __restrict__ woutt){
  const int b = blockIdx.x;
  if (b < 4096){
    size_t i = ((size_t)b * 256 + threadIdx.x) * 8;
    f32x4 v0 = *(const f32x4*)(x + i);
    f32x4 v1 = *(const f32x4*)(x + i + 4);
    s16x8 o;
#pragma unroll
    for (int j = 0; j < 4; ++j){ o[j] = f2bf(v0[j]); o[4+j] = f2bf(v1[j]); }
    *(s16x8*)(xb + i) = o;
  } else if (b < 7168){
    transp_body(Wqkv, wqkvt, DIM, D3, b - 4096);
  } else if (b < 11264){
    transp_body(W1, w1t, DIM, MLP, b - 7168);
  } else if (b < 15360){
    transp_body(W2, w2t, MLP, DIM, b - 11264);
  } else {
    transp_body(Wout, woutt, DIM, DIM, b - 15360);
  }
}

// ============================================================
// gemmCF (R7/R8 structure; R12 best): 128x128, 4 waves, 64KB LDS, 2 blocks/CU,
// counted-vmcnt ring, conflict-free k-group swizzle, LDS-staged epilogue.
// FUSED: K-range [0,K1) reads A/Bt, [K1,K1+K2) reads A2/Bt2.
// QKVEPI: q/k LayerNorm(d=64) + head-reorg (qln/kln) or V-transpose (vtb)
// directly from the LDS tile (tile is LN-closed; stride 130).
// ============================================================
template<int ACT, int FUSED, int QKVEPI>
__global__ __launch_bounds__(256, 2) void gemmCF(const short* __restrict__ A, const short* __restrict__ A2,
                                                 const short* __restrict__ Bt, const short* __restrict__ Bt2,
                                                 short* __restrict__ C,
                                                 const float* __restrict__ bias, const float* __restrict__ bias2,
                                                 int M, int N, int K1, int K2,
                                                 short* __restrict__ qln, short* __restrict__ kln,
                                                 short* __restrict__ vtb){
  __shared__ short lds[32768];

  const int tid = threadIdx.x;
  const int w = tid >> 6, lane = tid & 63;
  const int lr = lane & 15, g = lane >> 4;
  const int wr = w >> 1, wc = w & 1;
  const int NT1 = K1 >> 6;
  const int NT = NT1 + (FUSED ? (K2 >> 6) : 0);
  const int NIT = NT >> 1;

  const int nbn = N >> 7;
  const int cpx = gridDim.x >> 3;
  const int bid = (int)blockIdx.x;
  const int sw = (bid & 7)*cpx + (bid >> 3);
  const int nbn8 = nbn >> 3;
  const int T8 = sw >> 6, t64 = sw & 63;
  const int bm = (T8 / nbn8)*8 + (t64 >> 3);
  const int bn = (T8 % nbn8)*8 + (t64 & 7);

  const int l2 = lane >> 2;
  const int gsw = ((lane & 3) - ((lane >> 3) & 3)) & 3;
  const int cof = gsw * 8;
  const int qsw8 = ((g + (lr >> 1)) & 3) * 8;

  const short* ap0h = A  + (size_t)(bm*128 + w*16 + l2)*K1 + cof;
  const short* bp0h = Bt + (size_t)(bn*128 + w*16 + l2)*K1 + cof;
  const short* ap0a = FUSED ? (A2  + (size_t)(bm*128 + w*16 + l2)*K2 + cof) : nullptr;
  const short* bp0a = FUSED ? (Bt2 + (size_t)(bn*128 + w*16 + l2)*K2 + cof) : nullptr;

  auto stA = [&](int s, int T_, int kk){
    short* d0 = lds + s*4096 + w*512;
    if (FUSED && T_ >= NT1){
      size_t off = (size_t)(T_ - NT1)*64 + kk*32;
      gload16(ap0a + off, d0);
      gload16(ap0a + (size_t)64*K2 + off, d0 + 2048);
    } else {
      size_t off = (size_t)T_*64 + kk*32;
      gload16(ap0h + off, d0);
      gload16(ap0h + (size_t)64*K1 + off, d0 + 2048);
    }
  };
  auto stB = [&](int s, int T_, int kk){
    short* d0 = lds + 16384 + s*4096 + w*512;
    if (FUSED && T_ >= NT1){
      size_t off = (size_t)(T_ - NT1)*64 + kk*32;
      gload16(bp0a + off, d0);
      gload16(bp0a + (size_t)64*K2 + off, d0 + 2048);
    } else {
      size_t off = (size_t)T_*64 + kk*32;
      gload16(bp0h + off, d0);
      gload16(bp0h + (size_t)64*K1 + off, d0 + 2048);
    }
  };

#define LDA(s, mi) (*(const s16x8*)&lds[(s)*4096 + (wr*64 + (mi)*16 + lr)*32 + qsw8])
#define LDB(s, ni) (*(const s16x8*)&lds[16384 + (s)*4096 + (wc*64 + (ni)*16 + lr)*32 + qsw8])

  f32x4 acc[4][4] = {};
#define MM(ai, r) \
  acc[r][0]=mfma32(ai,b0,acc[r][0]); acc[r][1]=mfma32(ai,b1,acc[r][1]); \
  acc[r][2]=mfma32(ai,b2,acc[r][2]); acc[r][3]=mfma32(ai,b3,acc[r][3]);
#define RD(s) s16x8 a0=LDA(s,0),a1=LDA(s,1),a2=LDA(s,2),a3=LDA(s,3), \
                    b0=LDB(s,0),b1=LDB(s,1),b2=LDB(s,2),b3=LDB(s,3);
#define MM16 MM(a0,0) MM(a1,1) MM(a2,2) MM(a3,3)

  stA(0,0,0); stB(0,0,0);
  stA(1,0,1); stB(1,0,1);
  stA(2,1,0); stB(2,1,0);
  VMW8;
  PBAR;

  for (int i = 0; i < NIT; ++i){
    const int t = i << 1;
    const bool more = (i + 1 < NIT);
    {
      RD(0)
      stA(3, t+1, 1); stB(3, t+1, 1);
      PBAR; PRIO1; MM16 PRIO0;
      VMW8;
      PBAR;
    }
    {
      RD(1)
      if (more){ stA(0, t+2, 0); stB(0, t+2, 0); }
      PBAR; PRIO1; MM16 PRIO0;
      if (more){ VMW8; } else { VMW4; }
      PBAR;
    }
    {
      RD(2)
      if (more){ stA(1, t+2, 1); stB(1, t+2, 1); }
      PBAR; PRIO1; MM16 PRIO0;
      if (more){ VMW8; } else { VMW0; }
      PBAR;
    }
    {
      RD(3)
      if (more){ stA(2, t+3, 0); stB(2, t+3, 0); }
      PBAR; PRIO1; MM16 PRIO0;
      if (more){ VMW8; }
      PBAR;
    }
  }
#undef MM
#undef RD
#undef MM16
#undef LDA
#undef LDB

  if constexpr (QKVEPI){
    // ---- epilogue: LN(d=64)+reorg for q/k, transpose for v ----
#pragma unroll
    for (int a = 0; a < 4; ++a){
#pragma unroll
      for (int ni = 0; ni < 4; ++ni){
        const int col = wc*64 + ni*16 + lr;
        f32x4 v = acc[a][ni];
#pragma unroll
        for (int ii = 0; ii < 4; ++ii)
          lds[(wr*64 + a*16 + 4*g + ii)*130 + col] = f2bf(v[ii]);
      }
    }
    __syncthreads();
    const int part = (bn*128) >> 10;          // 0=q, 1=k, 2=v
    const int h0 = ((bn*128) & 1023) >> 6;    // first head in tile
    const int rg = bm*128;
    const int b = rg >> 11;
    const int tok0 = rg & 2047;

    if (part < 2){
      short* dstbase = part ? kln : qln;
      const float sc = part ? 1.f : 0.04508422003f;   // q: dim^-0.5 * log2(e)
      const int row = tid >> 1, grp = tid & 1;
      const short* src = &lds[row*130 + grp*64];
      float s = 0.f, sq = 0.f;
#pragma unroll
      for (int i2 = 0; i2 < 8; ++i2){
        s16x8 u = *(const s16x8*)(src + i2*8);
#pragma unroll
        for (int j = 0; j < 8; ++j){ float fv = b2f(u[j]); s += fv; sq += fv*fv; }
      }
      const float mu = s * (1.f/64.f);
      const float var = sq * (1.f/64.f) - mu*mu;
      const float inv = rsqrtf(var + 1e-5f) * sc;
      const int bh = b*16 + h0 + grp;
      short* dst = dstbase + ((size_t)bh*Nc + tok0 + row)*64;
#pragma unroll
      for (int i2 = 0; i2 < 8; ++i2){
        s16x8 u = *(const s16x8*)(src + i2*8);
        s16x8 o;
#pragma unroll
        for (int j = 0; j < 8; ++j) o[j] = f2bf((b2f(u[j]) - mu) * inv);
        *(s16x8*)(dst + i2*8) = o;
      }
    } else {
      // v: write vtb[bh][d][token]
      const int d = tid & 63, hh = (tid >> 6) & 1, half = tid >> 7;
      const int bh = b*16 + h0 + hh;
      short* dst = vtb + ((size_t)bh*64 + d)*Nc + tok0 + half*64;
#pragma unroll
      for (int i2 = 0; i2 < 8; ++i2){
        s16x8 o;
#pragma unroll
        for (int j = 0; j < 8; ++j)
          o[j] = lds[(half*64 + i2*8 + j)*130 + hh*64 + d];
        *(s16x8*)(dst + i2*8) = o;
      }
    }
    return;
  }

  // ---- normal epilogue: acc -> LDS (bf16) -> coalesced stores ----
#pragma unroll
  for (int a = 0; a < 4; ++a){
#pragma unroll
    for (int ni = 0; ni < 4; ++ni){
      const int col = wc*64 + ni*16 + lr;
      float bv = bias ? bias[bn*128 + col] : 0.f;
      if (FUSED && bias2) bv += bias2[bn*128 + col];
      f32x4 v = acc[a][ni];
#pragma unroll
      for (int ii = 0; ii < 4; ++ii){
        float val = v[ii] + bv;
        if constexpr (ACT) val = 0.5f*val*(1.f + erff(val*0.70710678118f));
        lds[(wr*64 + a*16 + 4*g + ii)*128 + col] = f2bf(val);
      }
    }
  }
  __syncthreads();
  const size_t crow0 = (size_t)bm * 128;
  const int ch = (tid & 15) * 8;
#pragma unroll
  for (int p = 0; p < 8; ++p){
    const int row = p*16 + (tid >> 4);
    *(s16x8*)&C[(crow0 + row)*N + bn*128 + ch] = *(const s16x8*)&lds[row*128 + ch];
  }
}

// ============================================================
// Flash attention (R8): KVBLK=64 dbuf, 1 barrier/kt, fused 2x32-key,
// swapped QK^T (32x32), exp2-domain softmax, defer-max, cvt_pk+permlane.
// ============================================================
__global__ __launch_bounds__(256) void attn_kern(const short* __restrict__ qln, const short* __restrict__ kln,
                                                 const short* __restrict__ vtb, short* __restrict__ attnv){
  __shared__ short Ks[2][64*72];
  __shared__ short Vs[2][64*72];
  const int tid = threadIdx.x;
  const int bh = blockIdx.x >> 4, qt = blockIdx.x & 15;
  const int b = bh >> 4, h = bh & 15;
  const int w = tid >> 6, lane = tid & 63;
  const int lq = lane & 31, hi = lane >> 5;
  const int qrow = qt*128 + w*32 + lq;

  const short* qp = qln + ((size_t)bh*Nc + qrow)*64 + hi*8;
  s16x8 qf[4];
#pragma unroll
  for (int m = 0; m < 4; ++m) qf[m] = *(const s16x8*)(qp + m*16);

  f32x16 o0 = {0,0,0,0,0,0,0,0,0,0,0,0,0,0,0,0};
  f32x16 o1 = {0,0,0,0,0,0,0,0,0,0,0,0,0,0,0,0};
  float mrun = -INFINITY, l = 0.f;

  const int sr = tid >> 3;
  const int sc = (tid & 7) * 8;
  const short* kb0 = kln + (size_t)bh*Nc*64;
  const short* vb0 = vtb + (size_t)bh*64*Nc;

  s16x8 kr0, kr1, vr0, vr1;
  {
    kr0 = *(const s16x8*)(kb0 + (size_t)sr*64 + sc);
    kr1 = *(const s16x8*)(kb0 + (size_t)(32 + sr)*64 + sc);
    vr0 = *(const s16x8*)(vb0 + (size_t)sr*Nc + sc);
    vr1 = *(const s16x8*)(vb0 + (size_t)(32 + sr)*Nc + sc);
  }

  for (int kt = 0; kt < 32; ++kt){
    const int cur = kt & 1;
    *(s16x8*)&Ks[cur][sr*72 + sc]        = kr0;
    *(s16x8*)&Ks[cur][(32 + sr)*72 + sc] = kr1;
    *(s16x8*)&Vs[cur][sr*72 + sc]        = vr0;
    *(s16x8*)&Vs[cur][(32 + sr)*72 + sc] = vr1;
    __syncthreads();
    if (kt + 1 < 32){
      const short* kb = kb0 + (size_t)(kt+1)*64*64;
      const short* vb = vb0 + (kt+1)*64;
      kr0 = *(const s16x8*)(kb + (size_t)sr*64 + sc);
      kr1 = *(const s16x8*)(kb + (size_t)(32 + sr)*64 + sc);
      vr0 = *(const s16x8*)(vb + (size_t)sr*Nc + sc);
      vr1 = *(const s16x8*)(vb + (size_t)(32 + sr)*Nc + sc);
    }

    f32x16 st0 = {0,0,0,0,0,0,0,0,0,0,0,0,0,0,0,0};
    f32x16 st1 = {0,0,0,0,0,0,0,0,0,0,0,0,0,0,0,0};
#pragma unroll
    for (int m = 0; m < 4; ++m){
      s16x8 kf0 = *(const s16x8*)&Ks[cur][ lq      *72 + m*16 + hi*8];
      s16x8 kf1 = *(const s16x8*)&Ks[cur][(32 + lq)*72 + m*16 + hi*8];
      st0 = mfma3216(kf0, qf[m], st0);
      st1 = mfma3216(kf1, qf[m], st1);
    }

    float cmax = max3f(st0[0], st0[1], st0[2]);
    cmax = max3f(cmax, st0[3], st0[4]);   cmax = max3f(cmax, st0[5], st0[6]);
    cmax = max3f(cmax, st0[7], st0[8]);   cmax = max3f(cmax, st0[9], st0[10]);
    cmax = max3f(cmax, st0[11], st0[12]); cmax = max3f(cmax, st0[13], st0[14]);
    cmax = max3f(cmax, st0[15], st1[0]);  cmax = max3f(cmax, st1[1], st1[2]);
    cmax = max3f(cmax, st1[3], st1[4]);   cmax = max3f(cmax, st1[5], st1[6]);
    cmax = max3f(cmax, st1[7], st1[8]);   cmax = max3f(cmax, st1[9], st1[10]);
    cmax = max3f(cmax, st1[11], st1[12]); cmax = max3f(cmax, st1[13], st1[14]);
    cmax = fmaxf(cmax, st1[15]);
    cmax = fmaxf(cmax, __shfl_xor(cmax, 32));
    if (__any(cmax > mrun + 8.f)){
      float mnew = fmaxf(mrun, cmax);
      float fr = EXP2F(mrun - mnew);
      l *= fr;
#pragma unroll
      for (int r = 0; r < 16; ++r){ o0[r] *= fr; o1[r] *= fr; }
      mrun = mnew;
    }
    float p0[16], p1[16];
#pragma unroll
    for (int r = 0; r < 16; ++r){
      p0[r] = EXP2F(st0[r] - mrun); l += p0[r];
      p1[r] = EXP2F(st1[r] - mrun); l += p1[r];
    }

#pragma unroll
    for (int kc = 0; kc < 2; ++kc){
      const float* p = kc ? p1 : p0;
#pragma unroll
      for (int kh = 0; kh < 2; ++kh){
        int r0 = kh*8;
        unsigned wa = cvtpk(p[r0+0], p[r0+1]);
        unsigned wb = cvtpk(p[r0+4], p[r0+5]);
        unsigned wc2 = cvtpk(p[r0+2], p[r0+3]);
        unsigned wd = cvtpk(p[r0+6], p[r0+7]);
        uint2v s1 = pl32swap(wa, wb);
        uint2v s2 = pl32swap(wc2, wd);
        union { unsigned u[4]; s16x8 v; } pu;
        pu.u[0] = s1[0]; pu.u[1] = s2[0]; pu.u[2] = s1[1]; pu.u[3] = s2[1];
        s16x8 vf0 = *(const s16x8*)&Vs[cur][ lq      *72 + kc*32 + kh*16 + hi*8];
        s16x8 vf1 = *(const s16x8*)&Vs[cur][(32 + lq)*72 + kc*32 + kh*16 + hi*8];
        o0 = mfma3216(vf0, pu.v, o0);
        o1 = mfma3216(vf1, pu.v, o1);
      }
    }
  }

  l += __shfl_xor(l, 32);
  float inv = 1.f / l;
  short* orow = attnv + ((size_t)(b*Nc + qrow))*DIM + h*64;
#pragma unroll
  for (int r = 0; r < 16; r += 2){
    int dv = (r&3) + 8*(r>>2) + 4*hi;
    *(unsigned*)&orow[dv]      = cvtpk(o0[r]*inv, o0[r+1]*inv);
    *(unsigned*)&orow[32 + dv] = cvtpk(o1[r]*inv, o1[r+1]*inv);
  }
}

// ============================================================
// out = LayerNorm(s2) over 1024, fp32 out
// ============================================================
__global__ __launch_bounds__(256) void final_ln(const short* __restrict__ s2, float* __restrict__ out){
  __shared__ float red[16];
  int row = blockIdx.x, tid = threadIdx.x;
  size_t base = (size_t)row*DIM + tid*4;
  s16x4 a = *(const s16x4*)(s2 + base);
  float v[4]; float s = 0.f, sq = 0.f;
#pragma unroll
  for (int i = 0; i < 4; ++i){ v[i] = b2f(a[i]); s += v[i]; sq += v[i]*v[i]; }
#pragma unroll
  for (int m = 1; m < 64; m <<= 1){ s += __shfl_xor(s, m); sq += __shfl_xor(sq, m); }
  int wv = tid >> 6;
  if ((tid & 63) == 0){ red[wv] = s; red[8 + wv] = sq; }
  __syncthreads();
  if (tid == 0){
    float S = red[0] + red[1] + red[2] + red[3];
    float Q = red[8] + red[9] + red[10] + red[11];
    float mu = S * (1.f/1024.f);
    float var = Q * (1.f/1024.f) - mu*mu;
    red[12] = mu; red[13] = rsqrtf(var + 1e-5f);
  }
  __syncthreads();
  float mu = red[12], inv = red[13];
#pragma unroll
  for (int i = 0; i < 4; ++i) out[base + i] = (v[i] - mu) * inv;
}

// ============================================================
extern "C" void kernel_launch(void* const* d_in, const int* in_sizes, int n_in,
                              void* d_out, int out_size, void* d_ws, size_t ws_size,
                              hipStream_t stream){
  const float* x    = (const float*)d_in[0];
  const float* Wqkv = (const float*)d_in[1];
  const float* W1   = (const float*)d_in[2];
  const float* b1   = (const float*)d_in[3];
  const float* W2   = (const float*)d_in[4];
  const float* b2   = (const float*)d_in[5];
  const float* Wout = (const float*)d_in[6];
  const float* bout = (const float*)d_in[7];
  float* out = (float*)d_out;
  char* ws = (char*)d_ws;

  short* xb    = (short*)(ws + OFF_XB);
  short* wqkvt = (short*)(ws + OFF_WQKVT);
  short* w1t   = (short*)(ws + OFF_W1T);
  short* w2t   = (short*)(ws + OFF_W2T);
  short* woutt = (short*)(ws + OFF_WOUTT);
  short* qln   = (short*)(ws + OFF_QLN);
  short* kln   = (short*)(ws + OFF_KLN);
  short* vtb   = (short*)(ws + OFF_VT);
  short* attnv = (short*)(ws + OFF_ATTNV);
  short* hbuf  = (short*)(ws + OFF_H);
  short* s2    = (short*)(ws + OFF_S2);

  // single prep launch: x->bf16 + all 4 weight transposes
  prep_all<<<16384, 256, 0, stream>>>(x, xb, Wqkv, wqkvt, W1, w1t, W2, w2t, Wout, woutt);

  // qkv gemm with fused q/k-LN + head-reorg + V-transpose epilogue (no qkv buffer)
  gemmCF<0,0,1><<<(Tc/128)*(D3/128), 256, 0, stream>>>(xb, xb, wqkvt, wqkvt, nullptr,
                                                       nullptr, nullptr, Tc, D3, DIM, DIM,
                                                       qln, kln, vtb);
  attn_kern<<<64*16, 256, 0, stream>>>(qln, kln, vtb, attnv);

  gemmCF<1,0,0><<<(Tc/128)*(MLP/128), 256, 0, stream>>>(xb, xb, w1t, w1t, hbuf,
                                                        b1, nullptr, Tc, MLP, DIM, DIM,
                                                        nullptr, nullptr, nullptr);
  // fused: s2 = hbuf@W2 + attnv@Wout + b2 + bout   (K = 4096 + 1024)
  gemmCF<0,1,0><<<(Tc/128)*(DIM/128), 256, 0, stream>>>(hbuf, attnv, w2t, woutt, s2,
                                                        b2, bout, Tc, DIM, MLP, DIM,
                                                        nullptr, nullptr, nullptr);

  final_ln<<<Tc, 256, 0, stream>>>(s2, out);
}

// Round 16
// 377.024 us; speedup vs baseline: 1.5209x; 1.0761x over previous
//
#include <hip/hip_runtime.h>

typedef __attribute__((ext_vector_type(8))) short s16x8;
typedef __attribute__((ext_vector_type(4))) short s16x4;
typedef __attribute__((ext_vector_type(4))) float f32x4;
typedef __attribute__((ext_vector_type(16))) float f32x16;
typedef __attribute__((ext_vector_type(2))) unsigned uint2v;

#define DEVINL __device__ __forceinline__

// ---------- bf16 helpers ----------
DEVINL float b2f(short u){ return __uint_as_float(((unsigned)(unsigned short)u) << 16); }
DEVINL short f2bf(float f){
  unsigned u = __float_as_uint(f);
  u += 0x7fffu + ((u >> 16) & 1u);
  return (short)(u >> 16);
}
DEVINL unsigned cvtpk(float lo, float hi){
  unsigned r;
  asm("v_cvt_pk_bf16_f32 %0, %1, %2" : "=v"(r) : "v"(lo), "v"(hi));
  return r;
}
DEVINL float max3f(float a, float b, float c){
  float r; asm("v_max3_f32 %0, %1, %2, %3" : "=v"(r) : "v"(a), "v"(b), "v"(c)); return r;
}

#if __has_builtin(__builtin_amdgcn_exp2f)
#define EXP2F __builtin_amdgcn_exp2f
#else
#define EXP2F exp2f
#endif

// ---------- MFMA wrappers ----------
DEVINL f32x4 mfma32(s16x8 a, s16x8 b, f32x4 c){
  return __builtin_amdgcn_mfma_f32_16x16x32_bf16(a, b, c, 0, 0, 0);
}
DEVINL f32x16 mfma3216(s16x8 a, s16x8 b, f32x16 c){
  return __builtin_amdgcn_mfma_f32_32x32x16_bf16(a, b, c, 0, 0, 0);
}

DEVINL uint2v pl32swap(unsigned a, unsigned b){
#if __has_builtin(__builtin_amdgcn_permlane32_swap)
  return __builtin_amdgcn_permlane32_swap(a, b, false, false);
#else
  asm volatile("v_permlane32_swap_b32 %0, %1" : "+v"(a), "+v"(b));
  uint2v r; r[0] = a; r[1] = b; return r;
#endif
}

// ---------- async global->LDS (width 16) ----------
typedef const unsigned __attribute__((address_space(1)))* gas1;
typedef unsigned __attribute__((address_space(3)))* las3;
DEVINL void gload16(const short* g, short* l){
  __builtin_amdgcn_global_load_lds((gas1)g, (las3)l, 16, 0, 0);
}

// ---------- sync primitives ----------
#define CFENCE asm volatile("" ::: "memory")
#define PBAR  do{ CFENCE; __builtin_amdgcn_sched_barrier(0); __builtin_amdgcn_s_barrier(); \
                  __builtin_amdgcn_sched_barrier(0); CFENCE; }while(0)
#define VMW8 asm volatile("s_waitcnt vmcnt(8)" ::: "memory")
#define VMW4 asm volatile("s_waitcnt vmcnt(4)" ::: "memory")
#define VMW0 asm volatile("s_waitcnt vmcnt(0)" ::: "memory")
#define PRIO1 __builtin_amdgcn_s_setprio(1)
#define PRIO0 __builtin_amdgcn_s_setprio(0)

// ---------- problem constants ----------
static const int Bc   = 4;
static const int Nc   = 2048;
static const int DIM  = 1024;
static const int Tc   = Bc * Nc;      // 8192 tokens
static const int MLP  = 4096;
static const int D3   = 3072;

// ---------- ws layout (bytes) — R16 overlap-aware, 159,383,552 total ----------
// Phase A prep1: writes xb, w1t, wqkvt.    Phase B qkv-gemm: xb,wqkvt -> qln,kln,vtb.
// Phase C merged: attn(qln,kln,vtb->attnv) || MLP1(xb,w1t->hbuf). wqkvt dead (under hbuf).
// Phase C2 prep2: W2,Wout -> w2t,woutt (over dead xb).
// Phase D fused: hbuf,attnv,w2t,woutt -> s2 (over dead qln).  Phase E: ln(s2)->out.
static const size_t OFF_XB    = 0;                    // 16 MiB
static const size_t OFF_W1T   = 16777216;             //  8 MiB
static const size_t OFF_QLN   = 25165824;             // 16 MiB
static const size_t OFF_KLN   = 41943040;             // 16 MiB
static const size_t OFF_VT    = 58720256;             // 16 MiB
static const size_t OFF_ATTNV = 75497472;             // 16 MiB
static const size_t OFF_HB    = 92274688;             // 64 MiB (end 159,383,552)
static const size_t OFF_WQKVT = OFF_HB;               //  6 MiB alias (dead before hbuf write)
static const size_t OFF_W2T   = 0;                    //  8 MiB over dead xb (phase D)
static const size_t OFF_WOUTT = 8388608;              //  2 MiB over dead xb (phase D)
static const size_t OFF_S2    = OFF_QLN;              // 16 MiB over dead qln (phase D)

// ============================================================
// transpose body (32x32 tiles)
// ============================================================
DEVINL void transp_body(const float* __restrict__ W, short* __restrict__ Wt,
                        int K, int N, int bid){
  __shared__ float tile[32][33];
  int ntx = N >> 5;
  int tx = bid % ntx, ty = bid / ntx;
  int r = threadIdx.x >> 3, c = (threadIdx.x & 7) * 4;
  f32x4 v = *(const f32x4*)(W + (size_t)(ty*32 + r)*N + tx*32 + c);
  tile[r][c] = v[0]; tile[r][c+1] = v[1]; tile[r][c+2] = v[2]; tile[r][c+3] = v[3];
  __syncthreads();
  s16x4 o;
#pragma unroll
  for (int j = 0; j < 4; ++j) o[j] = f2bf(tile[c+j][r]);
  *(s16x4*)(Wt + (size_t)(tx*32 + r)*K + ty*32 + c) = o;
}

// prep1: x->bf16 [0,4096) ; Wqkv->wqkvt [4096,7168) ; W1->w1t [7168,11264)
__global__ __launch_bounds__(256) void prep1(const float* __restrict__ x, short* __restrict__ xb,
                                             const float* __restrict__ Wqkv, short* __restrict__ wqkvt,
                                             const float* __restrict__ W1, short* __restrict__ w1t){
  const int b = blockIdx.x;
  if (b < 4096){
    size_t i = ((size_t)b * 256 + threadIdx.x) * 8;
    f32x4 v0 = *(const f32x4*)(x + i);
    f32x4 v1 = *(const f32x4*)(x + i + 4);
    s16x8 o;
#pragma unroll
    for (int j = 0; j < 4; ++j){ o[j] = f2bf(v0[j]); o[4+j] = f2bf(v1[j]); }
    *(s16x8*)(xb + i) = o;
  } else if (b < 7168){
    transp_body(Wqkv, wqkvt, DIM, D3, b - 4096);
  } else {
    transp_body(W1, w1t, DIM, MLP, b - 7168);
  }
}

// prep2: W2->w2t [0,4096) ; Wout->woutt [4096,5120)   (runs after merged; xb dead)
__global__ __launch_bounds__(256) void prep2(const float* __restrict__ W2, short* __restrict__ w2t,
                                             const float* __restrict__ Wout, short* __restrict__ woutt){
  const int b = blockIdx.x;
  if (b < 4096) transp_body(W2, w2t, MLP, DIM, b);
  else          transp_body(Wout, woutt, DIM, DIM, b - 4096);
}

// ============================================================
// gemmCF (R12 verified): 128x128, 4 waves, 64KB LDS, 2 blocks/CU,
// counted-vmcnt ring, conflict-free k-group swizzle, LDS-staged epilogue.
// FUSED: K-split A/Bt then A2/Bt2. QKVEPI: LN+reorg / V-transpose epilogue.
// ============================================================
template<int ACT, int FUSED, int QKVEPI>
__global__ __launch_bounds__(256, 2) void gemmCF(const short* __restrict__ A, const short* __restrict__ A2,
                                                 const short* __restrict__ Bt, const short* __restrict__ Bt2,
                                                 short* __restrict__ C,
                                                 const float* __restrict__ bias, const float* __restrict__ bias2,
                                                 int M, int N, int K1, int K2,
                                                 short* __restrict__ qln, short* __restrict__ kln,
                                                 short* __restrict__ vtb){
  __shared__ short lds[32768];

  const int tid = threadIdx.x;
  const int w = tid >> 6, lane = tid & 63;
  const int lr = lane & 15, g = lane >> 4;
  const int wr = w >> 1, wc = w & 1;
  const int NT1 = K1 >> 6;
  const int NT = NT1 + (FUSED ? (K2 >> 6) : 0);
  const int NIT = NT >> 1;

  const int nbn = N >> 7;
  const int cpx = gridDim.x >> 3;
  const int bid = (int)blockIdx.x;
  const int sw = (bid & 7)*cpx + (bid >> 3);
  const int nbn8 = nbn >> 3;
  const int T8 = sw >> 6, t64 = sw & 63;
  const int bm = (T8 / nbn8)*8 + (t64 >> 3);
  const int bn = (T8 % nbn8)*8 + (t64 & 7);

  const int l2 = lane >> 2;
  const int gsw = ((lane & 3) - ((lane >> 3) & 3)) & 3;
  const int cof = gsw * 8;
  const int qsw8 = ((g + (lr >> 1)) & 3) * 8;

  const short* ap0h = A  + (size_t)(bm*128 + w*16 + l2)*K1 + cof;
  const short* bp0h = Bt + (size_t)(bn*128 + w*16 + l2)*K1 + cof;
  const short* ap0a = FUSED ? (A2  + (size_t)(bm*128 + w*16 + l2)*K2 + cof) : nullptr;
  const short* bp0a = FUSED ? (Bt2 + (size_t)(bn*128 + w*16 + l2)*K2 + cof) : nullptr;

  auto stA = [&](int s, int T_, int kk){
    short* d0 = lds + s*4096 + w*512;
    if (FUSED && T_ >= NT1){
      size_t off = (size_t)(T_ - NT1)*64 + kk*32;
      gload16(ap0a + off, d0);
      gload16(ap0a + (size_t)64*K2 + off, d0 + 2048);
    } else {
      size_t off = (size_t)T_*64 + kk*32;
      gload16(ap0h + off, d0);
      gload16(ap0h + (size_t)64*K1 + off, d0 + 2048);
    }
  };
  auto stB = [&](int s, int T_, int kk){
    short* d0 = lds + 16384 + s*4096 + w*512;
    if (FUSED && T_ >= NT1){
      size_t off = (size_t)(T_ - NT1)*64 + kk*32;
      gload16(bp0a + off, d0);
      gload16(bp0a + (size_t)64*K2 + off, d0 + 2048);
    } else {
      size_t off = (size_t)T_*64 + kk*32;
      gload16(bp0h + off, d0);
      gload16(bp0h + (size_t)64*K1 + off, d0 + 2048);
    }
  };

#define LDA(s, mi) (*(const s16x8*)&lds[(s)*4096 + (wr*64 + (mi)*16 + lr)*32 + qsw8])
#define LDB(s, ni) (*(const s16x8*)&lds[16384 + (s)*4096 + (wc*64 + (ni)*16 + lr)*32 + qsw8])

  f32x4 acc[4][4] = {};
#define MM(ai, r) \
  acc[r][0]=mfma32(ai,b0,acc[r][0]); acc[r][1]=mfma32(ai,b1,acc[r][1]); \
  acc[r][2]=mfma32(ai,b2,acc[r][2]); acc[r][3]=mfma32(ai,b3,acc[r][3]);
#define RD(s) s16x8 a0=LDA(s,0),a1=LDA(s,1),a2=LDA(s,2),a3=LDA(s,3), \
                    b0=LDB(s,0),b1=LDB(s,1),b2=LDB(s,2),b3=LDB(s,3);
#define MM16 MM(a0,0) MM(a1,1) MM(a2,2) MM(a3,3)

  stA(0,0,0); stB(0,0,0);
  stA(1,0,1); stB(1,0,1);
  stA(2,1,0); stB(2,1,0);
  VMW8;
  PBAR;

  for (int i = 0; i < NIT; ++i){
    const int t = i << 1;
    const bool more = (i + 1 < NIT);
    {
      RD(0)
      stA(3, t+1, 1); stB(3, t+1, 1);
      PBAR; PRIO1; MM16 PRIO0;
      VMW8;
      PBAR;
    }
    {
      RD(1)
      if (more){ stA(0, t+2, 0); stB(0, t+2, 0); }
      PBAR; PRIO1; MM16 PRIO0;
      if (more){ VMW8; } else { VMW4; }
      PBAR;
    }
    {
      RD(2)
      if (more){ stA(1, t+2, 1); stB(1, t+2, 1); }
      PBAR; PRIO1; MM16 PRIO0;
      if (more){ VMW8; } else { VMW0; }
      PBAR;
    }
    {
      RD(3)
      if (more){ stA(2, t+3, 0); stB(2, t+3, 0); }
      PBAR; PRIO1; MM16 PRIO0;
      if (more){ VMW8; }
      PBAR;
    }
  }
#undef MM
#undef RD
#undef MM16
#undef LDA
#undef LDB

  if constexpr (QKVEPI){
#pragma unroll
    for (int a = 0; a < 4; ++a){
#pragma unroll
      for (int ni = 0; ni < 4; ++ni){
        const int col = wc*64 + ni*16 + lr;
        f32x4 v = acc[a][ni];
#pragma unroll
        for (int ii = 0; ii < 4; ++ii)
          lds[(wr*64 + a*16 + 4*g + ii)*130 + col] = f2bf(v[ii]);
      }
    }
    __syncthreads();
    const int part = (bn*128) >> 10;          // 0=q, 1=k, 2=v
    const int h0 = ((bn*128) & 1023) >> 6;
    const int rg = bm*128;
    const int b = rg >> 11;
    const int tok0 = rg & 2047;

    if (part < 2){
      short* dstbase = part ? kln : qln;
      const float sc = part ? 1.f : 0.04508422003f;   // q: dim^-0.5 * log2(e)
      const int row = tid >> 1, grp = tid & 1;
      const short* src = &lds[row*130 + grp*64];
      float s = 0.f, sq = 0.f;
#pragma unroll
      for (int i2 = 0; i2 < 8; ++i2){
        s16x8 u = *(const s16x8*)(src + i2*8);
#pragma unroll
        for (int j = 0; j < 8; ++j){ float fv = b2f(u[j]); s += fv; sq += fv*fv; }
      }
      const float mu = s * (1.f/64.f);
      const float var = sq * (1.f/64.f) - mu*mu;
      const float inv = rsqrtf(var + 1e-5f) * sc;
      const int bh = b*16 + h0 + grp;
      short* dst = dstbase + ((size_t)bh*Nc + tok0 + row)*64;
#pragma unroll
      for (int i2 = 0; i2 < 8; ++i2){
        s16x8 u = *(const s16x8*)(src + i2*8);
        s16x8 o;
#pragma unroll
        for (int j = 0; j < 8; ++j) o[j] = f2bf((b2f(u[j]) - mu) * inv);
        *(s16x8*)(dst + i2*8) = o;
      }
    } else {
      const int d = tid & 63, hh = (tid >> 6) & 1, half = tid >> 7;
      const int bh = b*16 + h0 + hh;
      short* dst = vtb + ((size_t)bh*64 + d)*Nc + tok0 + half*64;
#pragma unroll
      for (int i2 = 0; i2 < 8; ++i2){
        s16x8 o;
#pragma unroll
        for (int j = 0; j < 8; ++j)
          o[j] = lds[(half*64 + i2*8 + j)*130 + hh*64 + d];
        *(s16x8*)(dst + i2*8) = o;
      }
    }
    return;
  }

#pragma unroll
  for (int a = 0; a < 4; ++a){
#pragma unroll
    for (int ni = 0; ni < 4; ++ni){
      const int col = wc*64 + ni*16 + lr;
      float bv = bias ? bias[bn*128 + col] : 0.f;
      if (FUSED && bias2) bv += bias2[bn*128 + col];
      f32x4 v = acc[a][ni];
#pragma unroll
      for (int ii = 0; ii < 4; ++ii){
        float val = v[ii] + bv;
        if constexpr (ACT) val = 0.5f*val*(1.f + erff(val*0.70710678118f));
        lds[(wr*64 + a*16 + 4*g + ii)*128 + col] = f2bf(val);
      }
    }
  }
  __syncthreads();
  const size_t crow0 = (size_t)bm * 128;
  const int ch = (tid & 15) * 8;
#pragma unroll
  for (int p = 0; p < 8; ++p){
    const int row = p*16 + (tid >> 4);
    *(s16x8*)&C[(crow0 + row)*N + bn*128 + ch] = *(const s16x8*)&lds[row*128 + ch];
  }
}

// ============================================================
// attn body (R8, verified) — carved from attn_kern; smem: Ks=smem[0,9216),
// Vs=smem[9216,18432) shorts; [buf][64][72] each.
// ============================================================
DEVINL void attn_body(int bid, short* smem,
                      const short* __restrict__ qln, const short* __restrict__ kln,
                      const short* __restrict__ vtb, short* __restrict__ attnv){
  short* Ks = smem;
  short* Vs = smem + 9216;
  const int tid = threadIdx.x;
  const int bh = bid >> 4, qt = bid & 15;
  const int b = bh >> 4, h = bh & 15;
  const int w = tid >> 6, lane = tid & 63;
  const int lq = lane & 31, hi = lane >> 5;
  const int qrow = qt*128 + w*32 + lq;

  const short* qp = qln + ((size_t)bh*Nc + qrow)*64 + hi*8;
  s16x8 qf[4];
#pragma unroll
  for (int m = 0; m < 4; ++m) qf[m] = *(const s16x8*)(qp + m*16);

  f32x16 o0 = {0,0,0,0,0,0,0,0,0,0,0,0,0,0,0,0};
  f32x16 o1 = {0,0,0,0,0,0,0,0,0,0,0,0,0,0,0,0};
  float mrun = -INFINITY, l = 0.f;

  const int sr = tid >> 3;
  const int sc = (tid & 7) * 8;
  const short* kb0 = kln + (size_t)bh*Nc*64;
  const short* vb0 = vtb + (size_t)bh*64*Nc;

  s16x8 kr0, kr1, vr0, vr1;
  {
    kr0 = *(const s16x8*)(kb0 + (size_t)sr*64 + sc);
    kr1 = *(const s16x8*)(kb0 + (size_t)(32 + sr)*64 + sc);
    vr0 = *(const s16x8*)(vb0 + (size_t)sr*Nc + sc);
    vr1 = *(const s16x8*)(vb0 + (size_t)(32 + sr)*Nc + sc);
  }

  for (int kt = 0; kt < 32; ++kt){
    const int cur = kt & 1;
    *(s16x8*)&Ks[cur*4608 + sr*72 + sc]        = kr0;
    *(s16x8*)&Ks[cur*4608 + (32 + sr)*72 + sc] = kr1;
    *(s16x8*)&Vs[cur*4608 + sr*72 + sc]        = vr0;
    *(s16x8*)&Vs[cur*4608 + (32 + sr)*72 + sc] = vr1;
    __syncthreads();
    if (kt + 1 < 32){
      const short* kb = kb0 + (size_t)(kt+1)*64*64;
      const short* vb = vb0 + (kt+1)*64;
      kr0 = *(const s16x8*)(kb + (size_t)sr*64 + sc);
      kr1 = *(const s16x8*)(kb + (size_t)(32 + sr)*64 + sc);
      vr0 = *(const s16x8*)(vb + (size_t)sr*Nc + sc);
      vr1 = *(const s16x8*)(vb + (size_t)(32 + sr)*Nc + sc);
    }

    f32x16 st0 = {0,0,0,0,0,0,0,0,0,0,0,0,0,0,0,0};
    f32x16 st1 = {0,0,0,0,0,0,0,0,0,0,0,0,0,0,0,0};
#pragma unroll
    for (int m = 0; m < 4; ++m){
      s16x8 kf0 = *(const s16x8*)&Ks[cur*4608 +  lq      *72 + m*16 + hi*8];
      s16x8 kf1 = *(const s16x8*)&Ks[cur*4608 + (32 + lq)*72 + m*16 + hi*8];
      st0 = mfma3216(kf0, qf[m], st0);
      st1 = mfma3216(kf1, qf[m], st1);
    }

    float cmax = max3f(st0[0], st0[1], st0[2]);
    cmax = max3f(cmax, st0[3], st0[4]);   cmax = max3f(cmax, st0[5], st0[6]);
    cmax = max3f(cmax, st0[7], st0[8]);   cmax = max3f(cmax, st0[9], st0[10]);
    cmax = max3f(cmax, st0[11], st0[12]); cmax = max3f(cmax, st0[13], st0[14]);
    cmax = max3f(cmax, st0[15], st1[0]);  cmax = max3f(cmax, st1[1], st1[2]);
    cmax = max3f(cmax, st1[3], st1[4]);   cmax = max3f(cmax, st1[5], st1[6]);
    cmax = max3f(cmax, st1[7], st1[8]);   cmax = max3f(cmax, st1[9], st1[10]);
    cmax = max3f(cmax, st1[11], st1[12]); cmax = max3f(cmax, st1[13], st1[14]);
    cmax = fmaxf(cmax, st1[15]);
    cmax = fmaxf(cmax, __shfl_xor(cmax, 32));
    if (__any(cmax > mrun + 8.f)){
      float mnew = fmaxf(mrun, cmax);
      float fr = EXP2F(mrun - mnew);
      l *= fr;
#pragma unroll
      for (int r = 0; r < 16; ++r){ o0[r] *= fr; o1[r] *= fr; }
      mrun = mnew;
    }
    float p0[16], p1[16];
#pragma unroll
    for (int r = 0; r < 16; ++r){
      p0[r] = EXP2F(st0[r] - mrun); l += p0[r];
      p1[r] = EXP2F(st1[r] - mrun); l += p1[r];
    }

#pragma unroll
    for (int kc = 0; kc < 2; ++kc){
      const float* p = kc ? p1 : p0;
#pragma unroll
      for (int kh = 0; kh < 2; ++kh){
        int r0 = kh*8;
        unsigned wa = cvtpk(p[r0+0], p[r0+1]);
        unsigned wb = cvtpk(p[r0+4], p[r0+5]);
        unsigned wc2 = cvtpk(p[r0+2], p[r0+3]);
        unsigned wd = cvtpk(p[r0+6], p[r0+7]);
        uint2v s1 = pl32swap(wa, wb);
        uint2v s2 = pl32swap(wc2, wd);
        union { unsigned u[4]; s16x8 v; } pu;
        pu.u[0] = s1[0]; pu.u[1] = s2[0]; pu.u[2] = s1[1]; pu.u[3] = s2[1];
        s16x8 vf0 = *(const s16x8*)&Vs[cur*4608 +  lq      *72 + kc*32 + kh*16 + hi*8];
        s16x8 vf1 = *(const s16x8*)&Vs[cur*4608 + (32 + lq)*72 + kc*32 + kh*16 + hi*8];
        o0 = mfma3216(vf0, pu.v, o0);
        o1 = mfma3216(vf1, pu.v, o1);
      }
    }
  }

  l += __shfl_xor(l, 32);
  float inv = 1.f / l;
  short* orow = attnv + ((size_t)(b*Nc + qrow))*DIM + h*64;
#pragma unroll
  for (int r = 0; r < 16; r += 2){
    int dv = (r&3) + 8*(r>>2) + 4*hi;
    *(unsigned*)&orow[dv]      = cvtpk(o0[r]*inv, o0[r+1]*inv);
    *(unsigned*)&orow[32 + dv] = cvtpk(o1[r]*inv, o1[r+1]*inv);
  }
}

// ============================================================
// MLP1 body (gemmCF<1,0,0> specialization, N=4096, K=1024, virtual grid 2048)
// ============================================================
DEVINL void mlp1_body(int bid, short* lds,
                      const short* __restrict__ A, const short* __restrict__ Bt,
                      short* __restrict__ C, const float* __restrict__ bias){
  const int N = MLP, K1 = DIM;
  const int tid = threadIdx.x;
  const int w = tid >> 6, lane = tid & 63;
  const int lr = lane & 15, g = lane >> 4;
  const int wr = w >> 1, wc = w & 1;
  const int NIT = 8;   // NT=16

  const int nbn = N >> 7;            // 32
  const int cpx = 256;               // virtual grid 2048 / 8
  const int sw = (bid & 7)*cpx + (bid >> 3);
  const int nbn8 = nbn >> 3;         // 4
  const int T8 = sw >> 6, t64 = sw & 63;
  const int bm = (T8 / nbn8)*8 + (t64 >> 3);
  const int bn = (T8 % nbn8)*8 + (t64 & 7);

  const int l2 = lane >> 2;
  const int gsw = ((lane & 3) - ((lane >> 3) & 3)) & 3;
  const int cof = gsw * 8;
  const int qsw8 = ((g + (lr >> 1)) & 3) * 8;

  const short* ap0h = A  + (size_t)(bm*128 + w*16 + l2)*K1 + cof;
  const short* bp0h = Bt + (size_t)(bn*128 + w*16 + l2)*K1 + cof;

  auto stA = [&](int s, int T_, int kk){
    short* d0 = lds + s*4096 + w*512;
    size_t off = (size_t)T_*64 + kk*32;
    gload16(ap0h + off, d0);
    gload16(ap0h + (size_t)64*K1 + off, d0 + 2048);
  };
  auto stB = [&](int s, int T_, int kk){
    short* d0 = lds + 16384 + s*4096 + w*512;
    size_t off = (size_t)T_*64 + kk*32;
    gload16(bp0h + off, d0);
    gload16(bp0h + (size_t)64*K1 + off, d0 + 2048);
  };

#define LDA1(s, mi) (*(const s16x8*)&lds[(s)*4096 + (wr*64 + (mi)*16 + lr)*32 + qsw8])
#define LDB1(s, ni) (*(const s16x8*)&lds[16384 + (s)*4096 + (wc*64 + (ni)*16 + lr)*32 + qsw8])

  f32x4 acc[4][4] = {};
#define MM1(ai, r) \
  acc[r][0]=mfma32(ai,b0,acc[r][0]); acc[r][1]=mfma32(ai,b1,acc[r][1]); \
  acc[r][2]=mfma32(ai,b2,acc[r][2]); acc[r][3]=mfma32(ai,b3,acc[r][3]);
#define RD1(s) s16x8 a0=LDA1(s,0),a1=LDA1(s,1),a2=LDA1(s,2),a3=LDA1(s,3), \
                     b0=LDB1(s,0),b1=LDB1(s,1),b2=LDB1(s,2),b3=LDB1(s,3);
#define MM16_1 MM1(a0,0) MM1(a1,1) MM1(a2,2) MM1(a3,3)

  stA(0,0,0); stB(0,0,0);
  stA(1,0,1); stB(1,0,1);
  stA(2,1,0); stB(2,1,0);
  VMW8;
  PBAR;

  for (int i = 0; i < NIT; ++i){
    const int t = i << 1;
    const bool more = (i + 1 < NIT);
    {
      RD1(0)
      stA(3, t+1, 1); stB(3, t+1, 1);
      PBAR; PRIO1; MM16_1 PRIO0;
      VMW8;
      PBAR;
    }
    {
      RD1(1)
      if (more){ stA(0, t+2, 0); stB(0, t+2, 0); }
      PBAR; PRIO1; MM16_1 PRIO0;
      if (more){ VMW8; } else { VMW4; }
      PBAR;
    }
    {
      RD1(2)
      if (more){ stA(1, t+2, 1); stB(1, t+2, 1); }
      PBAR; PRIO1; MM16_1 PRIO0;
      if (more){ VMW8; } else { VMW0; }
      PBAR;
    }
    {
      RD1(3)
      if (more){ stA(2, t+3, 0); stB(2, t+3, 0); }
      PBAR; PRIO1; MM16_1 PRIO0;
      if (more){ VMW8; }
      PBAR;
    }
  }
#undef MM1
#undef RD1
#undef MM16_1
#undef LDA1
#undef LDB1

#pragma unroll
  for (int a = 0; a < 4; ++a){
#pragma unroll
    for (int ni = 0; ni < 4; ++ni){
      const int col = wc*64 + ni*16 + lr;
      const float bv = bias[bn*128 + col];
      f32x4 v = acc[a][ni];
#pragma unroll
      for (int ii = 0; ii < 4; ++ii){
        float val = v[ii] + bv;
        val = 0.5f*val*(1.f + erff(val*0.70710678118f));   // GELU
        lds[(wr*64 + a*16 + 4*g + ii)*128 + col] = f2bf(val);
      }
    }
  }
  __syncthreads();
  const size_t crow0 = (size_t)bm * 128;
  const int ch = (tid & 15) * 8;
#pragma unroll
  for (int p = 0; p < 8; ++p){
    const int row = p*16 + (tid >> 4);
    *(s16x8*)&C[(crow0 + row)*N + bn*128 + ch] = *(const s16x8*)&lds[row*128 + ch];
  }
}

// ============================================================
// merged: blocks [0,1024) = attention; [1024,3072) = MLP1 (independent)
// ============================================================
__global__ __launch_bounds__(256, 2) void attn_mlp1(const short* __restrict__ qln, const short* __restrict__ kln,
                                                    const short* __restrict__ vtb, short* __restrict__ attnv,
                                                    const short* __restrict__ xb, const short* __restrict__ w1t,
                                                    short* __restrict__ hbuf, const float* __restrict__ b1){
  __shared__ short smem[32768];
  const int bid = (int)blockIdx.x;
  if (bid < 1024){
    attn_body(bid, smem, qln, kln, vtb, attnv);
  } else {
    mlp1_body(bid - 1024, smem, xb, w1t, hbuf, b1);
  }
}

// ============================================================
// out = LayerNorm(s2) over 1024, fp32 out
// ============================================================
__global__ __launch_bounds__(256) void final_ln(const short* __restrict__ s2, float* __restrict__ out){
  __shared__ float red[16];
  int row = blockIdx.x, tid = threadIdx.x;
  size_t base = (size_t)row*DIM + tid*4;
  s16x4 a = *(const s16x4*)(s2 + base);
  float v[4]; float s = 0.f, sq = 0.f;
#pragma unroll
  for (int i = 0; i < 4; ++i){ v[i] = b2f(a[i]); s += v[i]; sq += v[i]*v[i]; }
#pragma unroll
  for (int m = 1; m < 64; m <<= 1){ s += __shfl_xor(s, m); sq += __shfl_xor(sq, m); }
  int wv = tid >> 6;
  if ((tid & 63) == 0){ red[wv] = s; red[8 + wv] = sq; }
  __syncthreads();
  if (tid == 0){
    float S = red[0] + red[1] + red[2] + red[3];
    float Q = red[8] + red[9] + red[10] + red[11];
    float mu = S * (1.f/1024.f);
    float var = Q * (1.f/1024.f) - mu*mu;
    red[12] = mu; red[13] = rsqrtf(var + 1e-5f);
  }
  __syncthreads();
  float mu = red[12], inv = red[13];
#pragma unroll
  for (int i = 0; i < 4; ++i) out[base + i] = (v[i] - mu) * inv;
}

// ============================================================
extern "C" void kernel_launch(void* const* d_in, const int* in_sizes, int n_in,
                              void* d_out, int out_size, void* d_ws, size_t ws_size,
                              hipStream_t stream){
  const float* x    = (const float*)d_in[0];
  const float* Wqkv = (const float*)d_in[1];
  const float* W1   = (const float*)d_in[2];
  const float* b1   = (const float*)d_in[3];
  const float* W2   = (const float*)d_in[4];
  const float* b2   = (const float*)d_in[5];
  const float* Wout = (const float*)d_in[6];
  const float* bout = (const float*)d_in[7];
  float* out = (float*)d_out;
  char* ws = (char*)d_ws;

  short* xb    = (short*)(ws + OFF_XB);
  short* w1t   = (short*)(ws + OFF_W1T);
  short* wqkvt = (short*)(ws + OFF_WQKVT);
  short* qln   = (short*)(ws + OFF_QLN);
  short* kln   = (short*)(ws + OFF_KLN);
  short* vtb   = (short*)(ws + OFF_VT);
  short* attnv = (short*)(ws + OFF_ATTNV);
  short* hbuf  = (short*)(ws + OFF_HB);
  short* w2t   = (short*)(ws + OFF_W2T);
  short* woutt = (short*)(ws + OFF_WOUTT);
  short* s2    = (short*)(ws + OFF_S2);

  // phase A: x->bf16, Wqkv/W1 transposes (one launch)
  prep1<<<11264, 256, 0, stream>>>(x, xb, Wqkv, wqkvt, W1, w1t);

  // phase B: qkv gemm + fused q/k-LN + head-reorg + V-transpose epilogue
  gemmCF<0,0,1><<<(Tc/128)*(D3/128), 256, 0, stream>>>(xb, xb, wqkvt, wqkvt, nullptr,
                                                       nullptr, nullptr, Tc, D3, DIM, DIM,
                                                       qln, kln, vtb);

  // phase C: attention || MLP1 (independent; one merged launch)
  attn_mlp1<<<1024 + 2048, 256, 0, stream>>>(qln, kln, vtb, attnv, xb, w1t, hbuf, b1);

  // phase C2: W2/Wout transposes into dead xb space
  prep2<<<5120, 256, 0, stream>>>(W2, w2t, Wout, woutt);

  // phase D: fused s2 = hbuf@W2 + attnv@Wout + b2 + bout  (K = 4096 + 1024)
  gemmCF<0,1,0><<<(Tc/128)*(DIM/128), 256, 0, stream>>>(hbuf, attnv, w2t, woutt, s2,
                                                        b2, bout, Tc, DIM, MLP, DIM,
                                                        nullptr, nullptr, nullptr);

  final_ln<<<Tc, 256, 0, stream>>>(s2, out);
}